// Round 2
// baseline (4680.629 us; speedup 1.0000x reference)
//
#include <hip/hip_runtime.h>
#include <hip/hip_bf16.h>
#include <hip/hip_fp16.h>

// Problem constants
#define B_      4
#define N_      2048
#define DIM_    128
#define HEADS_  8
#define HEAD_   128
#define INNER_  1024
#define QKV_    3072
#define EPS_    1e-5f
#define SCALE_  0.08838834764831845f   // HEAD^-0.5
// log2(10000)/64 for rope inv_freq = 2^(-i * this)
#define ROPE_C  0.20762050593046015f

// Workspace layout (floats): Q | K | V | O, each B*H*N*HEAD = 8388608 floats.
// Total 33554432 floats = 128 MiB.
#define QOFF 0
#define KOFF 8388608
#define VOFF 16777216
#define OOFF 25165824

// ---------------------------------------------------------------------------
// K1: fused LayerNorm + QKV projection + RoPE + scatter to [b,h,n,d]
// grid (128 row-tiles of 64, 48 e-tiles of 64), 256 threads
// LDS: xn[64][128] (32KB) + wt[64][128] swizzled (32KB) = 64KB
// NOTE reference ropes ALL heads, positions n=0..N-2; position N-1 unroped.
// ---------------------------------------------------------------------------
__global__ __launch_bounds__(256) void k_ln_qkv(
    const float* __restrict__ x, const float* __restrict__ gamma,
    const float* __restrict__ beta, const float* __restrict__ w,
    float* __restrict__ Q, float* __restrict__ K, float* __restrict__ V)
{
    __shared__ float xn[64 * 128];
    __shared__ float wt[64 * 128];
    const int t = threadIdx.x;
    const int row0 = blockIdx.x * 64;   // global row in [0,8192)
    const int e0   = blockIdx.y * 64;   // output col tile in [0,3072)

    // stage w tile (64 rows x 128 cols), XOR-swizzled chunks to spread banks
#pragma unroll
    for (int i = 0; i < 8; ++i) {
        int f = t + 256 * i;            // 0..2047 f4-chunks
        int r = f >> 5, c4 = f & 31;
        float4 w4 = *(const float4*)(w + (size_t)(e0 + r) * 128 + c4 * 4);
        int pc = c4 ^ ((r >> 2) & 7);
        *(float4*)&wt[r * 128 + pc * 4] = w4;
    }
    // LayerNorm: 4 threads per row, 32 elems each
    {
        int r = t >> 2, q4 = t & 3;
        const float* xr = x + (size_t)(row0 + r) * 128 + q4 * 32;
        float4 xa[8];
        float s = 0.f, s2 = 0.f;
#pragma unroll
        for (int i = 0; i < 8; ++i) {
            xa[i] = ((const float4*)xr)[i];
            s  += xa[i].x + xa[i].y + xa[i].z + xa[i].w;
            s2 += xa[i].x*xa[i].x + xa[i].y*xa[i].y + xa[i].z*xa[i].z + xa[i].w*xa[i].w;
        }
        s  += __shfl_xor(s, 1);  s2 += __shfl_xor(s2, 1);
        s  += __shfl_xor(s, 2);  s2 += __shfl_xor(s2, 2);
        float mu  = s * (1.f / 128.f);
        float var = s2 * (1.f / 128.f) - mu * mu;
        float rstd = rsqrtf(var + EPS_);
#pragma unroll
        for (int i = 0; i < 8; ++i) {
            int c = q4 * 32 + i * 4;
            float4 g  = *(const float4*)(gamma + c);
            float4 bb = *(const float4*)(beta + c);
            float4 o;
            o.x = (xa[i].x - mu) * rstd * g.x + bb.x;
            o.y = (xa[i].y - mu) * rstd * g.y + bb.y;
            o.z = (xa[i].z - mu) * rstd * g.z + bb.z;
            o.w = (xa[i].w - mu) * rstd * g.w + bb.w;
            *(float4*)&xn[r * 128 + c] = o;
        }
    }
    __syncthreads();

    // GEMM: 4 rows x 4 outs per thread
    const int tx = t & 15, ty = t >> 4;     // tx->outs, ty->rows
    float acc[4][4] = {};
#pragma unroll
    for (int c4 = 0; c4 < 32; ++c4) {
        int pc = c4 ^ (tx & 7);
        float4 wv[4], xv[4];
#pragma unroll
        for (int k = 0; k < 4; ++k)
            wv[k] = *(float4*)&wt[(tx * 4 + k) * 128 + pc * 4];
#pragma unroll
        for (int rr = 0; rr < 4; ++rr)
            xv[rr] = *(float4*)&xn[(ty * 4 + rr) * 128 + c4 * 4];
#pragma unroll
        for (int rr = 0; rr < 4; ++rr)
#pragma unroll
            for (int k = 0; k < 4; ++k)
                acc[rr][k] += xv[rr].x * wv[k].x + xv[rr].y * wv[k].y
                            + xv[rr].z * wv[k].z + xv[rr].w * wv[k].w;
    }

    // epilogue: rope (q,k; all heads; positions n < N-1) + scatter
    const int third = e0 >> 10;             // 0=q 1=k 2=v (block-uniform)
    const int h = (e0 & 1023) >> 7;
    float* dst = (third == 0) ? Q : (third == 1 ? K : V);
    const bool qk = (third < 2);
    const int d0 = (e0 & 127) + tx * 4;     // dim within head
    const int i0 = d0 >> 1;                 // rotary pair index of (d0,d0+1)
    float invf0 = exp2f(-(float)i0 * ROPE_C);
    float invf1 = exp2f(-(float)(i0 + 1) * ROPE_C);
#pragma unroll
    for (int rr = 0; rr < 4; ++rr) {
        int rg = row0 + ty * 4 + rr;
        int b = rg >> 11, n = rg & 2047;
        float v0 = acc[rr][0], v1 = acc[rr][1], v2 = acc[rr][2], v3 = acc[rr][3];
        if (qk && n != (N_ - 1)) {
            float th0 = (float)n * invf0, th1 = (float)n * invf1;
            float s0, c0, s1, c1;
            sincosf(th0, &s0, &c0);
            sincosf(th1, &s1, &c1);
            float nv0 = v0 * c0 - v1 * s0, nv1 = v1 * c0 + v0 * s0;
            float nv2 = v2 * c1 - v3 * s1, nv3 = v3 * c1 + v2 * s1;
            v0 = nv0; v1 = nv1; v2 = nv2; v3 = nv3;
        }
        size_t off = (((size_t)b * HEADS_ + h) * N_ + n) * HEAD_ + d0;
        *(float4*)(dst + off) = make_float4(v0, v1, v2, v3);
    }
}

// ---------------------------------------------------------------------------
// K2: attention. One block per (b,h, 8-query tile). 256 threads.
// Two-pass: scores (fp16 in LDS, fp32 logits math) -> softmax -> PV.
// LDS ~54.8KB -> 2 blocks/CU.
// ---------------------------------------------------------------------------
__global__ __launch_bounds__(256, 2) void k_attn(
    const float* __restrict__ Q, const float* __restrict__ K,
    const float* __restrict__ V, float* __restrict__ Op)
{
    __shared__ __align__(16) __half sc[8 * 2048];  // 32KB; reused as float[8*8*128] partials
    __shared__ float kv[32 * 132];                 // 16.9KB padded K/V tile
    __shared__ float qs[8 * 128];                  // 4KB
    __shared__ float red[8 * 32];
    __shared__ float mrow[8], linv[8];

    const int t = threadIdx.x;
    const int bid = blockIdx.x;
    const int bh = bid >> 8;        // 0..31  (b*8+h)
    const int qt = bid & 255;
    const int n0 = qt * 8;
    const float* Qb = Q + (size_t)bh * N_ * HEAD_;
    const float* Kb = K + (size_t)bh * N_ * HEAD_;
    const float* Vb = V + (size_t)bh * N_ * HEAD_;

    // stage q tile (8 x 128)
    {
        int r = t >> 5, c4 = t & 31;
        *(float4*)&qs[r * 128 + c4 * 4] =
            *(const float4*)(Qb + (size_t)(n0 + r) * 128 + c4 * 4);
    }
    __syncthreads();

    // q fragments in registers: lane owns 16-col slice (cs*16..+16) of all 8 rows
    const int cs = t & 7, jj = t >> 3;   // jj in 0..31
    float4 qr[8][4];
#pragma unroll
    for (int q = 0; q < 8; ++q)
#pragma unroll
        for (int c = 0; c < 4; ++c)
            qr[q][c] = *(float4*)&qs[q * 128 + cs * 16 + c * 4];

    // ---- pass 1: scores ----
    for (int jt = 0; jt < 64; ++jt) {
        __syncthreads();
#pragma unroll
        for (int i = 0; i < 4; ++i) {
            int f = t + 256 * i;  int r = f >> 5, c4 = f & 31;
            *(float4*)&kv[r * 132 + c4 * 4] =
                *(const float4*)(Kb + (size_t)(jt * 32 + r) * 128 + c4 * 4);
        }
        __syncthreads();
        float a8[8] = {0.f,0.f,0.f,0.f,0.f,0.f,0.f,0.f};
#pragma unroll
        for (int c = 0; c < 4; ++c) {
            float4 k4 = *(float4*)&kv[jj * 132 + cs * 16 + c * 4];
#pragma unroll
            for (int q = 0; q < 8; ++q)
                a8[q] += k4.x * qr[q][c].x + k4.y * qr[q][c].y
                       + k4.z * qr[q][c].z + k4.w * qr[q][c].w;
        }
#pragma unroll
        for (int q = 0; q < 8; ++q) a8[q] += __shfl_xor(a8[q], 1);
#pragma unroll
        for (int q = 0; q < 8; ++q) a8[q] += __shfl_xor(a8[q], 2);
#pragma unroll
        for (int q = 0; q < 8; ++q) a8[q] += __shfl_xor(a8[q], 4);
        // lane with c-slice cs writes row q=cs, col jt*32+jj
        sc[cs * 2048 + jt * 32 + jj] = __float2half(a8[cs] * SCALE_);
    }
    __syncthreads();

    // ---- softmax over each of 8 rows ----
    {
        int qq = t >> 5, cg = t & 31;
        float m_local = -1e30f;
#pragma unroll
        for (int i = 0; i < 32; ++i) {
            __half2 h2 = *(__half2*)&sc[qq * 2048 + 2 * (cg + 32 * i)];
            float2 f2 = __half22float2(h2);
            m_local = fmaxf(m_local, fmaxf(f2.x, f2.y));
        }
        red[qq * 32 + cg] = m_local;
        __syncthreads();
        if (t < 8) {
            float m = -1e30f;
            for (int i = 0; i < 32; ++i) m = fmaxf(m, red[t * 32 + i]);
            mrow[t] = m;
        }
        __syncthreads();
        float ml = mrow[qq];
        float s_local = 0.f;
#pragma unroll
        for (int i = 0; i < 32; ++i) {
            __half* p = &sc[qq * 2048 + 2 * (cg + 32 * i)];
            __half2 h2 = *(__half2*)p;
            float2 f2 = __half22float2(h2);
            float e0 = __expf(f2.x - ml), e1 = __expf(f2.y - ml);
            *(__half2*)p = __floats2half2_rn(e0, e1);
            s_local += e0 + e1;
        }
        red[qq * 32 + cg] = s_local;
        __syncthreads();
        if (t < 8) {
            float l = 0.f;
            for (int i = 0; i < 32; ++i) l += red[t * 32 + i];
            linv[t] = 1.f / l;
        }
    }

    // ---- pass 2: O = P * V ----
    const int dq = t & 31, jg = t >> 5;     // dq -> 4 dims, jg -> 4 j-rows of tile
    float4 acc4[8];
#pragma unroll
    for (int q = 0; q < 8; ++q) acc4[q] = make_float4(0.f, 0.f, 0.f, 0.f);
    for (int jt = 0; jt < 64; ++jt) {
        __syncthreads();
#pragma unroll
        for (int i = 0; i < 4; ++i) {
            int f = t + 256 * i;  int r = f >> 5, c4 = f & 31;
            *(float4*)&kv[r * 132 + c4 * 4] =
                *(const float4*)(Vb + (size_t)(jt * 32 + r) * 128 + c4 * 4);
        }
        __syncthreads();
        const int j0 = jg * 4;
        float p4[8][4];
#pragma unroll
        for (int q = 0; q < 8; ++q) {
            uint2 u = *(uint2*)&sc[q * 2048 + jt * 32 + j0];
            __half2 a = *(__half2*)&u.x, b2 = *(__half2*)&u.y;
            float2 fa = __half22float2(a), fb = __half22float2(b2);
            p4[q][0] = fa.x; p4[q][1] = fa.y; p4[q][2] = fb.x; p4[q][3] = fb.y;
        }
#pragma unroll
        for (int jx = 0; jx < 4; ++jx) {
            float4 v4 = *(float4*)&kv[(j0 + jx) * 132 + dq * 4];
#pragma unroll
            for (int q = 0; q < 8; ++q) {
                float p = p4[q][jx];
                acc4[q].x += p * v4.x; acc4[q].y += p * v4.y;
                acc4[q].z += p * v4.z; acc4[q].w += p * v4.w;
            }
        }
    }

    // reduce 8 jg-partials via LDS (reuse sc as float buffer)
    __syncthreads();
    float* scf = (float*)sc;
#pragma unroll
    for (int q = 0; q < 8; ++q)
        *(float4*)&scf[(jg * 8 + q) * 128 + dq * 4] = acc4[q];
    __syncthreads();
    {
        int q = t >> 5, d4 = t & 31;
        float4 s4 = make_float4(0.f, 0.f, 0.f, 0.f);
#pragma unroll
        for (int g = 0; g < 8; ++g) {
            float4 p4 = *(float4*)&scf[(g * 8 + q) * 128 + d4 * 4];
            s4.x += p4.x; s4.y += p4.y; s4.z += p4.z; s4.w += p4.w;
        }
        float il = linv[q];
        s4.x *= il; s4.y *= il; s4.z *= il; s4.w *= il;
        int b = bh >> 3, h = bh & 7;
        int n = n0 + q;
        *(float4*)(Op + (((size_t)b * N_ + n) * INNER_ + h * HEAD_ + d4 * 4)) = s4;
    }
}

// ---------------------------------------------------------------------------
// K4: output projection out[8192,128] = O[8192,1024] @ w_out^T + b_out
// grid (128 row-tiles of 64, 2 e-tiles of 64), 256 threads
// ---------------------------------------------------------------------------
__global__ __launch_bounds__(256) void k_proj(
    const float* __restrict__ O, const float* __restrict__ w,
    const float* __restrict__ bias, float* __restrict__ out)
{
    __shared__ float Ot[64 * 128];
    __shared__ float wt[64 * 128];
    const int t = threadIdx.x;
    const int row0 = blockIdx.x * 64;
    const int e0   = blockIdx.y * 64;
    const int tx = t & 15, ty = t >> 4;
    float acc[4][4] = {};
    for (int kt = 0; kt < 8; ++kt) {
        __syncthreads();
#pragma unroll
        for (int i = 0; i < 8; ++i) {
            int f = t + 256 * i;  int r = f >> 5, c4 = f & 31;
            *(float4*)&Ot[r * 128 + c4 * 4] =
                *(const float4*)(O + (size_t)(row0 + r) * 1024 + kt * 128 + c4 * 4);
            float4 w4 = *(const float4*)(w + (size_t)(e0 + r) * 1024 + kt * 128 + c4 * 4);
            int pc = c4 ^ ((r >> 2) & 7);
            *(float4*)&wt[r * 128 + pc * 4] = w4;
        }
        __syncthreads();
#pragma unroll
        for (int c4 = 0; c4 < 32; ++c4) {
            int pc = c4 ^ (tx & 7);
            float4 wv[4], xv[4];
#pragma unroll
            for (int k = 0; k < 4; ++k)
                wv[k] = *(float4*)&wt[(tx * 4 + k) * 128 + pc * 4];
#pragma unroll
            for (int rr = 0; rr < 4; ++rr)
                xv[rr] = *(float4*)&Ot[(ty * 4 + rr) * 128 + c4 * 4];
#pragma unroll
            for (int rr = 0; rr < 4; ++rr)
#pragma unroll
                for (int k = 0; k < 4; ++k)
                    acc[rr][k] += xv[rr].x * wv[k].x + xv[rr].y * wv[k].y
                                + xv[rr].z * wv[k].z + xv[rr].w * wv[k].w;
        }
    }
    float4 b4 = *(const float4*)(bias + e0 + tx * 4);
#pragma unroll
    for (int rr = 0; rr < 4; ++rr) {
        int rg = row0 + ty * 4 + rr;
        float4 o4;
        o4.x = acc[rr][0] + b4.x; o4.y = acc[rr][1] + b4.y;
        o4.z = acc[rr][2] + b4.z; o4.w = acc[rr][3] + b4.w;
        *(float4*)(out + (size_t)rg * 128 + e0 + tx * 4) = o4;
    }
}

// ---------------------------------------------------------------------------
extern "C" void kernel_launch(void* const* d_in, const int* in_sizes, int n_in,
                              void* d_out, int out_size, void* d_ws, size_t ws_size,
                              hipStream_t stream) {
    const float* x      = (const float*)d_in[0];
    const float* gamma  = (const float*)d_in[1];
    const float* beta   = (const float*)d_in[2];
    const float* w_qkv  = (const float*)d_in[3];
    const float* w_out  = (const float*)d_in[4];
    const float* b_out  = (const float*)d_in[5];
    float* out = (float*)d_out;
    float* ws  = (float*)d_ws;
    float* Q = ws + QOFF;
    float* K = ws + KOFF;
    float* V = ws + VOFF;
    float* O = ws + OOFF;

    k_ln_qkv<<<dim3(128, 48), 256, 0, stream>>>(x, gamma, beta, w_qkv, Q, K, V);
    k_attn  <<<dim3(8192),    256, 0, stream>>>(Q, K, V, O);
    k_proj  <<<dim3(128, 2),  256, 0, stream>>>(O, w_out, b_out, out);
}

// Round 3
// 2800.286 us; speedup vs baseline: 1.6715x; 1.6715x over previous
//
#include <hip/hip_runtime.h>
#include <hip/hip_bf16.h>
#include <hip/hip_fp16.h>

// Problem constants
#define B_      4
#define N_      2048
#define DIM_    128
#define HEADS_  8
#define HEAD_   128
#define INNER_  1024
#define QKV_    3072
#define EPS_    1e-5f
#define SCALE_  0.08838834764831845f   // HEAD^-0.5
// log2(10000)/64 for rope inv_freq = 2^(-i * this)
#define ROPE_C  0.20762050593046015f

typedef __attribute__((ext_vector_type(8))) short short8;   // 8 bf16 = 4 VGPRs
typedef __attribute__((ext_vector_type(4))) float f32x4;    // MFMA C/D

// Workspace layout: Q bf16 | K bf16 | Vt bf16 (each 16 MiB) | O fp32 (32 MiB)
#define QOFF_US  0
#define KOFF_US  8388608
#define VOFF_US  16777216
#define OOFF_F   12582912   // float index = 48 MiB / 4

// round-to-nearest-even float -> bf16 bits (finite inputs only)
__device__ __forceinline__ unsigned short f2bf(float f) {
    unsigned u = __builtin_bit_cast(unsigned, f);
    u = (u + 0x7fffu + ((u >> 16) & 1u)) >> 16;
    return (unsigned short)u;
}

// ---------------------------------------------------------------------------
// K1: fused LayerNorm + QKV projection + RoPE + bf16 scatter
// Q,K -> [bh][n][d] bf16 row-major; V -> [bh][d][n] bf16 (transposed for PV)
// grid (128 row-tiles of 64, 48 e-tiles of 64), 256 threads
// Reference ropes ALL heads at positions n=0..N-2; n=N-1 stays unroped.
// ---------------------------------------------------------------------------
__global__ __launch_bounds__(256) void k_ln_qkv(
    const float* __restrict__ x, const float* __restrict__ gamma,
    const float* __restrict__ beta, const float* __restrict__ w,
    unsigned short* __restrict__ Q, unsigned short* __restrict__ K,
    unsigned short* __restrict__ Vt)
{
    __shared__ float xn[64 * 128];
    __shared__ float wt[64 * 128];
    const int t = threadIdx.x;
    const int row0 = blockIdx.x * 64;   // global row in [0,8192)
    const int e0   = blockIdx.y * 64;   // output col tile in [0,3072)

#pragma unroll
    for (int i = 0; i < 8; ++i) {
        int f = t + 256 * i;            // 0..2047 f4-chunks
        int r = f >> 5, c4 = f & 31;
        float4 w4 = *(const float4*)(w + (size_t)(e0 + r) * 128 + c4 * 4);
        int pc = c4 ^ ((r >> 2) & 7);
        *(float4*)&wt[r * 128 + pc * 4] = w4;
    }
    {
        int r = t >> 2, q4 = t & 3;
        const float* xr = x + (size_t)(row0 + r) * 128 + q4 * 32;
        float4 xa[8];
        float s = 0.f, s2 = 0.f;
#pragma unroll
        for (int i = 0; i < 8; ++i) {
            xa[i] = ((const float4*)xr)[i];
            s  += xa[i].x + xa[i].y + xa[i].z + xa[i].w;
            s2 += xa[i].x*xa[i].x + xa[i].y*xa[i].y + xa[i].z*xa[i].z + xa[i].w*xa[i].w;
        }
        s  += __shfl_xor(s, 1);  s2 += __shfl_xor(s2, 1);
        s  += __shfl_xor(s, 2);  s2 += __shfl_xor(s2, 2);
        float mu  = s * (1.f / 128.f);
        float var = s2 * (1.f / 128.f) - mu * mu;
        float rstd = rsqrtf(var + EPS_);
#pragma unroll
        for (int i = 0; i < 8; ++i) {
            int c = q4 * 32 + i * 4;
            float4 g  = *(const float4*)(gamma + c);
            float4 bb = *(const float4*)(beta + c);
            float4 o;
            o.x = (xa[i].x - mu) * rstd * g.x + bb.x;
            o.y = (xa[i].y - mu) * rstd * g.y + bb.y;
            o.z = (xa[i].z - mu) * rstd * g.z + bb.z;
            o.w = (xa[i].w - mu) * rstd * g.w + bb.w;
            *(float4*)&xn[r * 128 + c] = o;
        }
    }
    __syncthreads();

    const int tx = t & 15, ty = t >> 4;
    float acc[4][4] = {};
#pragma unroll
    for (int c4 = 0; c4 < 32; ++c4) {
        int pc = c4 ^ (tx & 7);
        float4 wv[4], xv[4];
#pragma unroll
        for (int k = 0; k < 4; ++k)
            wv[k] = *(float4*)&wt[(tx * 4 + k) * 128 + pc * 4];
#pragma unroll
        for (int rr = 0; rr < 4; ++rr)
            xv[rr] = *(float4*)&xn[(ty * 4 + rr) * 128 + c4 * 4];
#pragma unroll
        for (int rr = 0; rr < 4; ++rr)
#pragma unroll
            for (int k = 0; k < 4; ++k)
                acc[rr][k] += xv[rr].x * wv[k].x + xv[rr].y * wv[k].y
                            + xv[rr].z * wv[k].z + xv[rr].w * wv[k].w;
    }

    // epilogue: rope (q,k; all heads; n < N-1) + bf16 scatter
    const int third = e0 >> 10;             // 0=q 1=k 2=v (block-uniform)
    const int h = (e0 & 1023) >> 7;
    const int d0 = (e0 & 127) + tx * 4;     // dim within head
    const int i0 = d0 >> 1;                 // rotary pair index
    const float invf0 = exp2f(-(float)i0 * ROPE_C);
    const float invf1 = exp2f(-(float)(i0 + 1) * ROPE_C);
#pragma unroll
    for (int rr = 0; rr < 4; ++rr) {
        int rg = row0 + ty * 4 + rr;
        int b = rg >> 11, n = rg & 2047;
        int bh = b * HEADS_ + h;
        float v0 = acc[rr][0], v1 = acc[rr][1], v2 = acc[rr][2], v3 = acc[rr][3];
        if (third < 2 && n != (N_ - 1)) {
            // theta in fp32 (matches reference), range-reduce in fp64, fast HW sin/cos
            float th0 = (float)n * invf0;
            float th1 = (float)n * invf1;
            double r0 = (double)th0 * 0.15915494309189535;  r0 -= floor(r0);
            double r1 = (double)th1 * 0.15915494309189535;  r1 -= floor(r1);
            float a0 = (float)r0 * 6.283185307179586f;
            float a1 = (float)r1 * 6.283185307179586f;
            float s0 = __sinf(a0), c0 = __cosf(a0);
            float s1 = __sinf(a1), c1 = __cosf(a1);
            float nv0 = v0 * c0 - v1 * s0, nv1 = v1 * c0 + v0 * s0;
            float nv2 = v2 * c1 - v3 * s1, nv3 = v3 * c1 + v2 * s1;
            v0 = nv0; v1 = nv1; v2 = nv2; v3 = nv3;
        }
        if (third < 2) {
            unsigned short* dst = (third == 0) ? Q : K;
            unsigned short p4[4] = { f2bf(v0), f2bf(v1), f2bf(v2), f2bf(v3) };
            *(uint2*)(dst + ((size_t)bh * N_ + n) * HEAD_ + d0) = *(uint2*)p4;
        } else {
            // Vt[bh][d][n]
            unsigned short* dst = Vt + ((size_t)bh * HEAD_) * N_ + n;
            dst[(size_t)(d0 + 0) * N_] = f2bf(v0);
            dst[(size_t)(d0 + 1) * N_] = f2bf(v1);
            dst[(size_t)(d0 + 2) * N_] = f2bf(v2);
            dst[(size_t)(d0 + 3) * N_] = f2bf(v3);
        }
    }
}

// ---------------------------------------------------------------------------
// K2: flash attention, bf16 MFMA 16x16x32, online softmax.
// Block = 64 q-rows (4 waves x 16), iterate 32 key-tiles of 64.
// LDS: K-tile 64x136 bf16, Vt-tile 128x72 bf16, P 4x16x72 bf16 (~45 KB).
// Verified layouts: A[m=lane&15][k=quad*8+j], B[n=lane&15][k=quad*8+j],
//                   C/D row=quad*4+reg, col=lane&15.
// ---------------------------------------------------------------------------
__global__ __launch_bounds__(256) void k_attn(
    const unsigned short* __restrict__ Q, const unsigned short* __restrict__ K,
    const unsigned short* __restrict__ Vt, float* __restrict__ Op)
{
    __shared__ unsigned short lK[64 * 136];
    __shared__ unsigned short lV[128 * 72];
    __shared__ unsigned short lP[4 * 16 * 72];

    const int t = threadIdx.x;
    const int w = t >> 6, l = t & 63;
    const int lm = l & 15, quad = l >> 4;
    const int bid = blockIdx.x;
    const int bh = bid & 31;          // b*8+h ; adjacent blocks spread bh over XCDs
    const int qt = bid >> 5;          // 0..31
    const int n0 = qt * 64;
    const unsigned short* Qb = Q  + (size_t)bh * N_ * HEAD_;
    const unsigned short* Kb = K  + (size_t)bh * N_ * HEAD_;
    const unsigned short* Vb = Vt + (size_t)bh * N_ * HEAD_;   // [128][2048]

    // persistent Q A-fragments: rows n0+w*16+lm, k-groups quad*8
    short8 aq[4];
    {
        const unsigned short* qp = Qb + ((size_t)(n0 + w * 16 + lm)) * 128 + quad * 8;
#pragma unroll
        for (int ks = 0; ks < 4; ++ks)
            aq[ks] = *(const short8*)(qp + ks * 32);
    }

    f32x4 Oa[8];
#pragma unroll
    for (int i = 0; i < 8; ++i) Oa[i] = (f32x4){0.f, 0.f, 0.f, 0.f};
    float mrun[4] = {-1e30f, -1e30f, -1e30f, -1e30f};
    float lrun[4] = {0.f, 0.f, 0.f, 0.f};

    for (int jt = 0; jt < 32; ++jt) {
        __syncthreads();
        // stage K-tile (64 keys x 128 d) and Vt-tile (128 d x 64 keys)
#pragma unroll
        for (int i = 0; i < 4; ++i) {
            int c = t + 256 * i;                 // 0..1023 16B chunks
            int r = c >> 4, cc = c & 15;
            *(short8*)&lK[r * 136 + cc * 8] =
                *(const short8*)(Kb + ((size_t)(jt * 64 + r)) * 128 + cc * 8);
        }
#pragma unroll
        for (int i = 0; i < 4; ++i) {
            int c = t + 256 * i;
            int r = c >> 3, cc = c & 7;
            *(short8*)&lV[r * 72 + cc * 8] =
                *(const short8*)(Vb + (size_t)r * N_ + jt * 64 + cc * 8);
        }
        __syncthreads();

        // S = Q K^T  (16 q-rows x 64 keys per wave)
        f32x4 S[4];
#pragma unroll
        for (int nb = 0; nb < 4; ++nb) {
            S[nb] = (f32x4){0.f, 0.f, 0.f, 0.f};
#pragma unroll
            for (int ks = 0; ks < 4; ++ks) {
                short8 bk = *(short8*)&lK[(nb * 16 + lm) * 136 + ks * 32 + quad * 8];
                S[nb] = __builtin_amdgcn_mfma_f32_16x16x32_bf16(aq[ks], bk, S[nb], 0, 0, 0);
            }
        }
#pragma unroll
        for (int nb = 0; nb < 4; ++nb)
#pragma unroll
            for (int r = 0; r < 4; ++r) S[nb][r] *= SCALE_;

        // online softmax stats (rows quad*4+r; reduce over the 16 lanes of a quad)
        float mt[4];
#pragma unroll
        for (int r = 0; r < 4; ++r)
            mt[r] = fmaxf(fmaxf(S[0][r], S[1][r]), fmaxf(S[2][r], S[3][r]));
#pragma unroll
        for (int off = 1; off <= 8; off <<= 1)
#pragma unroll
            for (int r = 0; r < 4; ++r)
                mt[r] = fmaxf(mt[r], __shfl_xor(mt[r], off));
        float al[4];
#pragma unroll
        for (int r = 0; r < 4; ++r) {
            float nm = fmaxf(mrun[r], mt[r]);
            al[r] = __expf(mrun[r] - nm);
            mrun[r] = nm;
        }
        float rs[4] = {0.f, 0.f, 0.f, 0.f};
        unsigned short pb[4][4];
#pragma unroll
        for (int nb = 0; nb < 4; ++nb)
#pragma unroll
            for (int r = 0; r < 4; ++r) {
                float p = __expf(S[nb][r] - mrun[r]);
                rs[r] += p;
                pb[nb][r] = f2bf(p);
            }
#pragma unroll
        for (int off = 1; off <= 8; off <<= 1)
#pragma unroll
            for (int r = 0; r < 4; ++r) rs[r] += __shfl_xor(rs[r], off);
#pragma unroll
        for (int r = 0; r < 4; ++r) lrun[r] = lrun[r] * al[r] + rs[r];

        // rescale O accumulators
#pragma unroll
        for (int nb8 = 0; nb8 < 8; ++nb8)
#pragma unroll
            for (int r = 0; r < 4; ++r) Oa[nb8][r] *= al[r];

        // P (C/D layout) -> LDS row-major -> A-operand layout; wave-private region
        unsigned short* lPw = &lP[w * 16 * 72];
#pragma unroll
        for (int nb = 0; nb < 4; ++nb)
#pragma unroll
            for (int r = 0; r < 4; ++r)
                lPw[(quad * 4 + r) * 72 + nb * 16 + lm] = pb[nb][r];
        // (within-wave LDS dependency; compiler inserts lgkmcnt wait)

        // O += P V   (k-dim = 64 keys = 2 mfma steps)
#pragma unroll
        for (int ks2 = 0; ks2 < 2; ++ks2) {
            short8 ap = *(short8*)&lPw[lm * 72 + ks2 * 32 + quad * 8];
#pragma unroll
            for (int nb8 = 0; nb8 < 8; ++nb8) {
                short8 bv = *(short8*)&lV[(nb8 * 16 + lm) * 72 + ks2 * 32 + quad * 8];
                Oa[nb8] = __builtin_amdgcn_mfma_f32_16x16x32_bf16(ap, bv, Oa[nb8], 0, 0, 0);
            }
        }
    }

    // epilogue: divide by l, store fp32 O[b][n][h*128+d]
    const int b = bh >> 3, h = bh & 7;
#pragma unroll
    for (int r = 0; r < 4; ++r) {
        float il = 1.f / lrun[r];
        int n = n0 + w * 16 + quad * 4 + r;
        float* op = Op + ((size_t)b * N_ + n) * INNER_ + h * HEAD_ + lm;
#pragma unroll
        for (int nb8 = 0; nb8 < 8; ++nb8)
            op[nb8 * 16] = Oa[nb8][r] * il;
    }
}

// ---------------------------------------------------------------------------
// K4: output projection out[8192,128] = O[8192,1024] @ w_out^T + b_out (fp32)
// ---------------------------------------------------------------------------
__global__ __launch_bounds__(256) void k_proj(
    const float* __restrict__ O, const float* __restrict__ w,
    const float* __restrict__ bias, float* __restrict__ out)
{
    __shared__ float Ot[64 * 128];
    __shared__ float wt[64 * 128];
    const int t = threadIdx.x;
    const int row0 = blockIdx.x * 64;
    const int e0   = blockIdx.y * 64;
    const int tx = t & 15, ty = t >> 4;
    float acc[4][4] = {};
    for (int kt = 0; kt < 8; ++kt) {
        __syncthreads();
#pragma unroll
        for (int i = 0; i < 8; ++i) {
            int f = t + 256 * i;  int r = f >> 5, c4 = f & 31;
            *(float4*)&Ot[r * 128 + c4 * 4] =
                *(const float4*)(O + (size_t)(row0 + r) * 1024 + kt * 128 + c4 * 4);
            float4 w4 = *(const float4*)(w + (size_t)(e0 + r) * 1024 + kt * 128 + c4 * 4);
            int pc = c4 ^ ((r >> 2) & 7);
            *(float4*)&wt[r * 128 + pc * 4] = w4;
        }
        __syncthreads();
#pragma unroll
        for (int c4 = 0; c4 < 32; ++c4) {
            int pc = c4 ^ (tx & 7);
            float4 wv[4], xv[4];
#pragma unroll
            for (int k = 0; k < 4; ++k)
                wv[k] = *(float4*)&wt[(tx * 4 + k) * 128 + pc * 4];
#pragma unroll
            for (int rr = 0; rr < 4; ++rr)
                xv[rr] = *(float4*)&Ot[(ty * 4 + rr) * 128 + c4 * 4];
#pragma unroll
            for (int rr = 0; rr < 4; ++rr)
#pragma unroll
                for (int k = 0; k < 4; ++k)
                    acc[rr][k] += xv[rr].x * wv[k].x + xv[rr].y * wv[k].y
                                + xv[rr].z * wv[k].z + xv[rr].w * wv[k].w;
        }
    }
    float4 b4 = *(const float4*)(bias + e0 + tx * 4);
#pragma unroll
    for (int rr = 0; rr < 4; ++rr) {
        int rg = row0 + ty * 4 + rr;
        float4 o4;
        o4.x = acc[rr][0] + b4.x; o4.y = acc[rr][1] + b4.y;
        o4.z = acc[rr][2] + b4.z; o4.w = acc[rr][3] + b4.w;
        *(float4*)(out + (size_t)rg * 128 + e0 + tx * 4) = o4;
    }
}

// ---------------------------------------------------------------------------
extern "C" void kernel_launch(void* const* d_in, const int* in_sizes, int n_in,
                              void* d_out, int out_size, void* d_ws, size_t ws_size,
                              hipStream_t stream) {
    const float* x      = (const float*)d_in[0];
    const float* gamma  = (const float*)d_in[1];
    const float* beta   = (const float*)d_in[2];
    const float* w_qkv  = (const float*)d_in[3];
    const float* w_out  = (const float*)d_in[4];
    const float* b_out  = (const float*)d_in[5];
    float* out = (float*)d_out;
    unsigned short* wsu = (unsigned short*)d_ws;
    unsigned short* Q   = wsu + QOFF_US;
    unsigned short* K   = wsu + KOFF_US;
    unsigned short* Vt  = wsu + VOFF_US;
    float* O            = (float*)d_ws + OOFF_F;

    k_ln_qkv<<<dim3(128, 48), 256, 0, stream>>>(x, gamma, beta, w_qkv, Q, K, Vt);
    k_attn  <<<dim3(1024),    256, 0, stream>>>(Q, K, Vt, O);
    k_proj  <<<dim3(128, 2),  256, 0, stream>>>(O, w_out, b_out, out);
}

// Round 4
// 478.665 us; speedup vs baseline: 9.7785x; 5.8502x over previous
//
#include <hip/hip_runtime.h>
#include <hip/hip_bf16.h>
#include <hip/hip_fp16.h>

// Problem constants
#define B_      4
#define N_      2048
#define DIM_    128
#define HEADS_  8
#define HEAD_   128
#define INNER_  1024
#define QKV_    3072
#define EPS_    1e-5f
#define SCALE_  0.08838834764831845f   // HEAD^-0.5
// log2(10000)/64 for rope inv_freq = 2^(-i * this)
#define ROPE_C  0.20762050593046015f

typedef __attribute__((ext_vector_type(8))) short short8;   // 8 bf16 = 4 VGPRs
typedef __attribute__((ext_vector_type(4))) float f32x4;    // MFMA C/D

// Workspace (byte offsets):
//  Q   [0,16M)  K [16M,32M)  Vt [32M,48M)   (bf16, [bh][n][d] / [bh][d][n])
//  qkv [48M,96M) bf16 [8192][3072]  -- dead after k_rope; O fp32 reuses [48M,80M)
//  xn  [96M,100M) fp32 [8192][128]

__device__ __forceinline__ unsigned short f2bf(float f) {
    unsigned u = __builtin_bit_cast(unsigned, f);
    u = (u + 0x7fffu + ((u >> 16) & 1u)) >> 16;
    return (unsigned short)u;
}
__device__ __forceinline__ float bf2f(unsigned short h) {
    unsigned u = ((unsigned)h) << 16;
    return __builtin_bit_cast(float, u);
}
__device__ __forceinline__ unsigned pk2(float a, float b) {
    return (unsigned)f2bf(a) | ((unsigned)f2bf(b) << 16);
}

// ---------------------------------------------------------------------------
// K0: LayerNorm -> fp32 xn. One wave per row, lane holds 2 elems.
// ---------------------------------------------------------------------------
__global__ __launch_bounds__(256) void k_ln(
    const float* __restrict__ x, const float* __restrict__ g,
    const float* __restrict__ be, float* __restrict__ xn)
{
    const int w = threadIdx.x >> 6, l = threadIdx.x & 63;
    const int row = blockIdx.x * 4 + w;
    float2 v = *(const float2*)(x + (size_t)row * 128 + l * 2);
    float s = v.x + v.y, s2 = v.x * v.x + v.y * v.y;
#pragma unroll
    for (int off = 1; off < 64; off <<= 1) {
        s  += __shfl_xor(s, off);
        s2 += __shfl_xor(s2, off);
    }
    float mu = s * (1.f / 128.f);
    float var = s2 * (1.f / 128.f) - mu * mu;
    float rs = rsqrtf(var + EPS_);
    float2 gg = *(const float2*)(g + l * 2);
    float2 bb = *(const float2*)(be + l * 2);
    float2 o;
    o.x = (v.x - mu) * rs * gg.x + bb.x;
    o.y = (v.y - mu) * rs * gg.y + bb.y;
    *(float2*)(xn + (size_t)row * 128 + l * 2) = o;
}

// ---------------------------------------------------------------------------
// K1: QKV GEMM, bf16 MFMA 16x16x32. qkv[row][e] = sum_k xn[row][k]*w[e][k].
// Block: M=64 rows x N=128 cols, K=128 in one shot. 4 waves, wave = 16 rows.
// LDS: lA 64x136 bf16 (17KB, reused for C) + lB 128x136 bf16 (34KB) = 52KB.
// Converts fp32->bf16 during staging. Grid (128, 24).
// ---------------------------------------------------------------------------
__global__ __launch_bounds__(256) void k_qkv_gemm(
    const float* __restrict__ xn, const float* __restrict__ w,
    unsigned short* __restrict__ qkv)
{
    __shared__ unsigned short lA[64 * 136];
    __shared__ unsigned short lB[128 * 136];
    const int t = threadIdx.x;
    const int wv = t >> 6, l = t & 63;
    const int lm = l & 15, quad = l >> 4;
    const int row0 = blockIdx.x * 64;
    const int e0   = blockIdx.y * 128;

    // stage A (64x128) fp32->bf16
#pragma unroll
    for (int i = 0; i < 4; ++i) {
        int c = t + 256 * i;  int r = c >> 4, c8 = c & 15;
        const float* src = xn + (size_t)(row0 + r) * 128 + c8 * 8;
        float4 f0 = *(const float4*)src, f1 = *(const float4*)(src + 4);
        uint4 u = { pk2(f0.x, f0.y), pk2(f0.z, f0.w), pk2(f1.x, f1.y), pk2(f1.z, f1.w) };
        *(uint4*)&lA[r * 136 + c8 * 8] = u;
    }
    // stage B (128x128) fp32->bf16
#pragma unroll
    for (int i = 0; i < 8; ++i) {
        int c = t + 256 * i;  int r = c >> 4, c8 = c & 15;
        const float* src = w + (size_t)(e0 + r) * 128 + c8 * 8;
        float4 f0 = *(const float4*)src, f1 = *(const float4*)(src + 4);
        uint4 u = { pk2(f0.x, f0.y), pk2(f0.z, f0.w), pk2(f1.x, f1.y), pk2(f1.z, f1.w) };
        *(uint4*)&lB[r * 136 + c8 * 8] = u;
    }
    __syncthreads();

    // A fragments: wave rows wv*16+lm, k = ks*32 + quad*8
    short8 af[4];
#pragma unroll
    for (int ks = 0; ks < 4; ++ks)
        af[ks] = *(short8*)&lA[(wv * 16 + lm) * 136 + ks * 32 + quad * 8];

    f32x4 acc[8];
#pragma unroll
    for (int ct = 0; ct < 8; ++ct) acc[ct] = (f32x4){0.f, 0.f, 0.f, 0.f};
#pragma unroll
    for (int ks = 0; ks < 4; ++ks) {
        short8 a = af[ks];
#pragma unroll
        for (int ct = 0; ct < 8; ++ct) {
            short8 b = *(short8*)&lB[(ct * 16 + lm) * 136 + ks * 32 + quad * 8];
            acc[ct] = __builtin_amdgcn_mfma_f32_16x16x32_bf16(a, b, acc[ct], 0, 0, 0);
        }
    }
    __syncthreads();

    // C (C/D layout) -> LDS (reuse lA) -> coalesced bf16 store
#pragma unroll
    for (int ct = 0; ct < 8; ++ct)
#pragma unroll
        for (int r = 0; r < 4; ++r)
            lA[(wv * 16 + quad * 4 + r) * 136 + ct * 16 + lm] = f2bf(acc[ct][r]);
    __syncthreads();
#pragma unroll
    for (int i = 0; i < 4; ++i) {
        int c = t + 256 * i;  int r = c >> 4, c8 = c & 15;
        *(uint4*)(qkv + (size_t)(row0 + r) * QKV_ + e0 + c8 * 8) =
            *(uint4*)&lA[r * 136 + c8 * 8];
    }
}

// ---------------------------------------------------------------------------
// K2: rope Q,K (all heads, n < N-1) + scatter; V -> Vt transpose via LDS.
// Grid (bh=32, nt=32); block handles 64 n-rows of one (b,h).
// ---------------------------------------------------------------------------
__global__ __launch_bounds__(256) void k_rope(
    const unsigned short* __restrict__ qkv, unsigned short* __restrict__ Q,
    unsigned short* __restrict__ K, unsigned short* __restrict__ Vt)
{
    __shared__ unsigned lT[128 * 65];   // u32 slots holding bf16 (transpose tile)
    const int t = threadIdx.x;
    const int bh = blockIdx.x;          // b*8+h
    const int n0 = blockIdx.y * 64;
    const int b = bh >> 3, h = bh & 7;
    const int nn = t >> 2, lg = t & 3;
    const int n = n0 + nn;
    const size_t rowb = ((size_t)b * N_ + n) * QKV_;

    // ---- Q and K with rope ----
#pragma unroll
    for (int part = 0; part < 2; ++part) {
        const int coff = part * 1024 + h * 128;
        unsigned short* dst = part == 0 ? Q : K;
#pragma unroll
        for (int jj = 0; jj < 4; ++jj) {
            const int d0 = (lg + jj * 4) * 8;
            short8 vv = *(const short8*)(qkv + rowb + coff + d0);
            unsigned short* pv = (unsigned short*)&vv;
            if (n != N_ - 1) {
#pragma unroll
                for (int p = 0; p < 4; ++p) {
                    int i0 = (d0 >> 1) + p;
                    float invf = exp2f(-(float)i0 * ROPE_C);
                    float th = (float)n * invf;
                    float cs = __cosf(th), sn = __sinf(th);
                    float e = bf2f(pv[2 * p]), o = bf2f(pv[2 * p + 1]);
                    pv[2 * p]     = f2bf(e * cs - o * sn);
                    pv[2 * p + 1] = f2bf(o * cs + e * sn);
                }
            }
            *(short8*)(dst + ((size_t)bh * N_ + n) * HEAD_ + d0) = vv;
        }
    }

    // ---- V transpose: lT[d][nn] (pad 65 -> <=2-way banks both phases) ----
#pragma unroll
    for (int jj = 0; jj < 4; ++jj) {
        const int d0 = (lg + jj * 4) * 8;
        short8 vv = *(const short8*)(qkv + rowb + 2048 + h * 128 + d0);
        unsigned short* pv = (unsigned short*)&vv;
#pragma unroll
        for (int j = 0; j < 8; ++j)
            lT[(d0 + j) * 65 + nn] = pv[j];
    }
    __syncthreads();
    {
        const int d = t >> 1, half = t & 1;
        unsigned short ob[32];
#pragma unroll
        for (int i = 0; i < 32; ++i)
            ob[i] = (unsigned short)lT[d * 65 + half * 32 + i];
        unsigned short* dst = Vt + ((size_t)bh * HEAD_ + d) * N_ + n0 + half * 32;
#pragma unroll
        for (int i = 0; i < 4; ++i)
            *(short8*)(dst + i * 8) = *(short8*)&ob[i * 8];
    }
}

// ---------------------------------------------------------------------------
// K3: flash attention, bf16 MFMA 16x16x32, online softmax. (unchanged)
// ---------------------------------------------------------------------------
__global__ __launch_bounds__(256) void k_attn(
    const unsigned short* __restrict__ Q, const unsigned short* __restrict__ K,
    const unsigned short* __restrict__ Vt, float* __restrict__ Op)
{
    __shared__ unsigned short lK[64 * 136];
    __shared__ unsigned short lV[128 * 72];
    __shared__ unsigned short lP[4 * 16 * 72];

    const int t = threadIdx.x;
    const int w = t >> 6, l = t & 63;
    const int lm = l & 15, quad = l >> 4;
    const int bid = blockIdx.x;
    const int bh = bid & 31;
    const int qt = bid >> 5;
    const int n0 = qt * 64;
    const unsigned short* Qb = Q  + (size_t)bh * N_ * HEAD_;
    const unsigned short* Kb = K  + (size_t)bh * N_ * HEAD_;
    const unsigned short* Vb = Vt + (size_t)bh * N_ * HEAD_;

    short8 aq[4];
    {
        const unsigned short* qp = Qb + ((size_t)(n0 + w * 16 + lm)) * 128 + quad * 8;
#pragma unroll
        for (int ks = 0; ks < 4; ++ks)
            aq[ks] = *(const short8*)(qp + ks * 32);
    }

    f32x4 Oa[8];
#pragma unroll
    for (int i = 0; i < 8; ++i) Oa[i] = (f32x4){0.f, 0.f, 0.f, 0.f};
    float mrun[4] = {-1e30f, -1e30f, -1e30f, -1e30f};
    float lrun[4] = {0.f, 0.f, 0.f, 0.f};

    for (int jt = 0; jt < 32; ++jt) {
        __syncthreads();
#pragma unroll
        for (int i = 0; i < 4; ++i) {
            int c = t + 256 * i;
            int r = c >> 4, cc = c & 15;
            *(short8*)&lK[r * 136 + cc * 8] =
                *(const short8*)(Kb + ((size_t)(jt * 64 + r)) * 128 + cc * 8);
        }
#pragma unroll
        for (int i = 0; i < 4; ++i) {
            int c = t + 256 * i;
            int r = c >> 3, cc = c & 7;
            *(short8*)&lV[r * 72 + cc * 8] =
                *(const short8*)(Vb + (size_t)r * N_ + jt * 64 + cc * 8);
        }
        __syncthreads();

        f32x4 S[4];
#pragma unroll
        for (int nb = 0; nb < 4; ++nb) {
            S[nb] = (f32x4){0.f, 0.f, 0.f, 0.f};
#pragma unroll
            for (int ks = 0; ks < 4; ++ks) {
                short8 bk = *(short8*)&lK[(nb * 16 + lm) * 136 + ks * 32 + quad * 8];
                S[nb] = __builtin_amdgcn_mfma_f32_16x16x32_bf16(aq[ks], bk, S[nb], 0, 0, 0);
            }
        }
#pragma unroll
        for (int nb = 0; nb < 4; ++nb)
#pragma unroll
            for (int r = 0; r < 4; ++r) S[nb][r] *= SCALE_;

        float mt[4];
#pragma unroll
        for (int r = 0; r < 4; ++r)
            mt[r] = fmaxf(fmaxf(S[0][r], S[1][r]), fmaxf(S[2][r], S[3][r]));
#pragma unroll
        for (int off = 1; off <= 8; off <<= 1)
#pragma unroll
            for (int r = 0; r < 4; ++r)
                mt[r] = fmaxf(mt[r], __shfl_xor(mt[r], off));
        float al[4];
#pragma unroll
        for (int r = 0; r < 4; ++r) {
            float nm = fmaxf(mrun[r], mt[r]);
            al[r] = __expf(mrun[r] - nm);
            mrun[r] = nm;
        }
        float rs[4] = {0.f, 0.f, 0.f, 0.f};
        unsigned short pb[4][4];
#pragma unroll
        for (int nb = 0; nb < 4; ++nb)
#pragma unroll
            for (int r = 0; r < 4; ++r) {
                float p = __expf(S[nb][r] - mrun[r]);
                rs[r] += p;
                pb[nb][r] = f2bf(p);
            }
#pragma unroll
        for (int off = 1; off <= 8; off <<= 1)
#pragma unroll
            for (int r = 0; r < 4; ++r) rs[r] += __shfl_xor(rs[r], off);
#pragma unroll
        for (int r = 0; r < 4; ++r) lrun[r] = lrun[r] * al[r] + rs[r];

#pragma unroll
        for (int nb8 = 0; nb8 < 8; ++nb8)
#pragma unroll
            for (int r = 0; r < 4; ++r) Oa[nb8][r] *= al[r];

        unsigned short* lPw = &lP[w * 16 * 72];
#pragma unroll
        for (int nb = 0; nb < 4; ++nb)
#pragma unroll
            for (int r = 0; r < 4; ++r)
                lPw[(quad * 4 + r) * 72 + nb * 16 + lm] = pb[nb][r];

#pragma unroll
        for (int ks2 = 0; ks2 < 2; ++ks2) {
            short8 ap = *(short8*)&lPw[lm * 72 + ks2 * 32 + quad * 8];
#pragma unroll
            for (int nb8 = 0; nb8 < 8; ++nb8) {
                short8 bv = *(short8*)&lV[(nb8 * 16 + lm) * 72 + ks2 * 32 + quad * 8];
                Oa[nb8] = __builtin_amdgcn_mfma_f32_16x16x32_bf16(ap, bv, Oa[nb8], 0, 0, 0);
            }
        }
    }

    const int b = bh >> 3, h = bh & 7;
#pragma unroll
    for (int r = 0; r < 4; ++r) {
        float il = 1.f / lrun[r];
        int n = n0 + w * 16 + quad * 4 + r;
        float* op = Op + ((size_t)b * N_ + n) * INNER_ + h * HEAD_ + lm;
#pragma unroll
        for (int nb8 = 0; nb8 < 8; ++nb8)
            op[nb8 * 16] = Oa[nb8][r] * il;
    }
}

// ---------------------------------------------------------------------------
// K4: output projection out[8192,128] = O[8192,1024] @ w_out^T + b_out (fp32)
// ---------------------------------------------------------------------------
__global__ __launch_bounds__(256) void k_proj(
    const float* __restrict__ O, const float* __restrict__ w,
    const float* __restrict__ bias, float* __restrict__ out)
{
    __shared__ float Ot[64 * 128];
    __shared__ float wt[64 * 128];
    const int t = threadIdx.x;
    const int row0 = blockIdx.x * 64;
    const int e0   = blockIdx.y * 64;
    const int tx = t & 15, ty = t >> 4;
    float acc[4][4] = {};
    for (int kt = 0; kt < 8; ++kt) {
        __syncthreads();
#pragma unroll
        for (int i = 0; i < 8; ++i) {
            int f = t + 256 * i;  int r = f >> 5, c4 = f & 31;
            *(float4*)&Ot[r * 128 + c4 * 4] =
                *(const float4*)(O + (size_t)(row0 + r) * 1024 + kt * 128 + c4 * 4);
            float4 w4 = *(const float4*)(w + (size_t)(e0 + r) * 1024 + kt * 128 + c4 * 4);
            int pc = c4 ^ ((r >> 2) & 7);
            *(float4*)&wt[r * 128 + pc * 4] = w4;
        }
        __syncthreads();
#pragma unroll
        for (int c4 = 0; c4 < 32; ++c4) {
            int pc = c4 ^ (tx & 7);
            float4 wv[4], xv[4];
#pragma unroll
            for (int k = 0; k < 4; ++k)
                wv[k] = *(float4*)&wt[(tx * 4 + k) * 128 + pc * 4];
#pragma unroll
            for (int rr = 0; rr < 4; ++rr)
                xv[rr] = *(float4*)&Ot[(ty * 4 + rr) * 128 + c4 * 4];
#pragma unroll
            for (int rr = 0; rr < 4; ++rr)
#pragma unroll
                for (int k = 0; k < 4; ++k)
                    acc[rr][k] += xv[rr].x * wv[k].x + xv[rr].y * wv[k].y
                                + xv[rr].z * wv[k].z + xv[rr].w * wv[k].w;
        }
    }
    float4 b4 = *(const float4*)(bias + e0 + tx * 4);
#pragma unroll
    for (int rr = 0; rr < 4; ++rr) {
        int rg = row0 + ty * 4 + rr;
        float4 o4;
        o4.x = acc[rr][0] + b4.x; o4.y = acc[rr][1] + b4.y;
        o4.z = acc[rr][2] + b4.z; o4.w = acc[rr][3] + b4.w;
        *(float4*)(out + (size_t)rg * 128 + e0 + tx * 4) = o4;
    }
}

// ---------------------------------------------------------------------------
extern "C" void kernel_launch(void* const* d_in, const int* in_sizes, int n_in,
                              void* d_out, int out_size, void* d_ws, size_t ws_size,
                              hipStream_t stream) {
    const float* x      = (const float*)d_in[0];
    const float* gamma  = (const float*)d_in[1];
    const float* beta   = (const float*)d_in[2];
    const float* w_qkv  = (const float*)d_in[3];
    const float* w_out  = (const float*)d_in[4];
    const float* b_out  = (const float*)d_in[5];
    float* out = (float*)d_out;
    char* wsb = (char*)d_ws;
    unsigned short* Q   = (unsigned short*)(wsb);
    unsigned short* K   = (unsigned short*)(wsb + (16ull << 20));
    unsigned short* Vt  = (unsigned short*)(wsb + (32ull << 20));
    unsigned short* qkv = (unsigned short*)(wsb + (48ull << 20));
    float* xn           = (float*)(wsb + (96ull << 20));
    float* O            = (float*)(wsb + (48ull << 20));   // reuses qkv region

    k_ln       <<<dim3(2048),    256, 0, stream>>>(x, gamma, beta, xn);
    k_qkv_gemm <<<dim3(128, 24), 256, 0, stream>>>(xn, w_qkv, qkv);
    k_rope     <<<dim3(32, 32),  256, 0, stream>>>(qkv, Q, K, Vt);
    k_attn     <<<dim3(1024),    256, 0, stream>>>(Q, K, Vt, O);
    k_proj     <<<dim3(128, 2),  256, 0, stream>>>(O, w_out, b_out, out);
}

// Round 7
// 441.730 us; speedup vs baseline: 10.5961x; 1.0836x over previous
//
#include <hip/hip_runtime.h>
#include <hip/hip_bf16.h>
#include <hip/hip_fp16.h>

// Problem constants
#define B_      4
#define N_      2048
#define DIM_    128
#define HEADS_  8
#define HEAD_   128
#define INNER_  1024
#define QKV_    3072
#define EPS_    1e-5f
#define SCALE_  0.08838834764831845f   // HEAD^-0.5
// log2(10000)/64 for rope inv_freq = 2^(-i * this)
#define ROPE_C  0.20762050593046015f

typedef __attribute__((ext_vector_type(8))) short short8;   // 8 bf16 = 4 VGPRs
typedef __attribute__((ext_vector_type(4))) float f32x4;    // MFMA C/D

// Workspace (byte offsets) — R4 layout:
//  Q   [0,16M)  K [16M,32M)  Vt [32M,48M)   (bf16)
//  qkv [48M,96M) bf16 [8192][3072] -- dead after k_rope; O fp32 reuses [48M,80M)
//  xn  [96M,100M) fp32 [8192][128]

__device__ __forceinline__ unsigned short f2bf(float f) {
    unsigned u = __builtin_bit_cast(unsigned, f);
    u = (u + 0x7fffu + ((u >> 16) & 1u)) >> 16;
    return (unsigned short)u;
}
__device__ __forceinline__ float bf2f(unsigned short h) {
    unsigned u = ((unsigned)h) << 16;
    return __builtin_bit_cast(float, u);
}
__device__ __forceinline__ unsigned pk2(float a, float b) {
    return (unsigned)f2bf(a) | ((unsigned)f2bf(b) << 16);
}

// ---------------------------------------------------------------------------
// K0: LayerNorm -> fp32 xn. One wave per row, lane holds 2 elems.
// ---------------------------------------------------------------------------
__global__ __launch_bounds__(256) void k_ln(
    const float* __restrict__ x, const float* __restrict__ g,
    const float* __restrict__ be, float* __restrict__ xn)
{
    const int w = threadIdx.x >> 6, l = threadIdx.x & 63;
    const int row = blockIdx.x * 4 + w;
    float2 v = *(const float2*)(x + (size_t)row * 128 + l * 2);
    float s = v.x + v.y, s2 = v.x * v.x + v.y * v.y;
#pragma unroll
    for (int off = 1; off < 64; off <<= 1) {
        s  += __shfl_xor(s, off);
        s2 += __shfl_xor(s2, off);
    }
    float mu = s * (1.f / 128.f);
    float var = s2 * (1.f / 128.f) - mu * mu;
    float rs = rsqrtf(var + EPS_);
    float2 gg = *(const float2*)(g + l * 2);
    float2 bb = *(const float2*)(be + l * 2);
    float2 o;
    o.x = (v.x - mu) * rs * gg.x + bb.x;
    o.y = (v.y - mu) * rs * gg.y + bb.y;
    *(float2*)(xn + (size_t)row * 128 + l * 2) = o;
}

// ---------------------------------------------------------------------------
// K1: QKV GEMM, bf16 MFMA 16x16x32 -> qkv buffer (R4-validated version)
// ---------------------------------------------------------------------------
__global__ __launch_bounds__(256) void k_qkv_gemm(
    const float* __restrict__ xn, const float* __restrict__ w,
    unsigned short* __restrict__ qkv)
{
    __shared__ unsigned short lA[64 * 136];
    __shared__ unsigned short lB[128 * 136];
    const int t = threadIdx.x;
    const int wv = t >> 6, l = t & 63;
    const int lm = l & 15, quad = l >> 4;
    const int row0 = blockIdx.x * 64;
    const int e0   = blockIdx.y * 128;

#pragma unroll
    for (int i = 0; i < 4; ++i) {
        int c = t + 256 * i;  int r = c >> 4, c8 = c & 15;
        const float* src = xn + (size_t)(row0 + r) * 128 + c8 * 8;
        float4 f0 = *(const float4*)src, f1 = *(const float4*)(src + 4);
        uint4 u = { pk2(f0.x, f0.y), pk2(f0.z, f0.w), pk2(f1.x, f1.y), pk2(f1.z, f1.w) };
        *(uint4*)&lA[r * 136 + c8 * 8] = u;
    }
#pragma unroll
    for (int i = 0; i < 8; ++i) {
        int c = t + 256 * i;  int r = c >> 4, c8 = c & 15;
        const float* src = w + (size_t)(e0 + r) * 128 + c8 * 8;
        float4 f0 = *(const float4*)src, f1 = *(const float4*)(src + 4);
        uint4 u = { pk2(f0.x, f0.y), pk2(f0.z, f0.w), pk2(f1.x, f1.y), pk2(f1.z, f1.w) };
        *(uint4*)&lB[r * 136 + c8 * 8] = u;
    }
    __syncthreads();

    short8 af[4];
#pragma unroll
    for (int ks = 0; ks < 4; ++ks)
        af[ks] = *(short8*)&lA[(wv * 16 + lm) * 136 + ks * 32 + quad * 8];

    f32x4 acc[8];
#pragma unroll
    for (int ct = 0; ct < 8; ++ct) acc[ct] = (f32x4){0.f, 0.f, 0.f, 0.f};
#pragma unroll
    for (int ks = 0; ks < 4; ++ks) {
        short8 a = af[ks];
#pragma unroll
        for (int ct = 0; ct < 8; ++ct) {
            short8 b = *(short8*)&lB[(ct * 16 + lm) * 136 + ks * 32 + quad * 8];
            acc[ct] = __builtin_amdgcn_mfma_f32_16x16x32_bf16(a, b, acc[ct], 0, 0, 0);
        }
    }
    __syncthreads();

#pragma unroll
    for (int ct = 0; ct < 8; ++ct)
#pragma unroll
        for (int r = 0; r < 4; ++r)
            lA[(wv * 16 + quad * 4 + r) * 136 + ct * 16 + lm] = f2bf(acc[ct][r]);
    __syncthreads();
#pragma unroll
    for (int i = 0; i < 4; ++i) {
        int c = t + 256 * i;  int r = c >> 4, c8 = c & 15;
        *(uint4*)(qkv + (size_t)(row0 + r) * QKV_ + e0 + c8 * 8) =
            *(uint4*)&lA[r * 136 + c8 * 8];
    }
}

// ---------------------------------------------------------------------------
// K2: rope Q,K (all heads, n < N-1) + scatter; V -> Vt transpose via LDS.
// (R4-validated version)
// ---------------------------------------------------------------------------
__global__ __launch_bounds__(256) void k_rope(
    const unsigned short* __restrict__ qkv, unsigned short* __restrict__ Q,
    unsigned short* __restrict__ K, unsigned short* __restrict__ Vt)
{
    __shared__ unsigned lT[128 * 65];
    const int t = threadIdx.x;
    const int bh = blockIdx.x;
    const int n0 = blockIdx.y * 64;
    const int b = bh >> 3, h = bh & 7;
    const int nn = t >> 2, lg = t & 3;
    const int n = n0 + nn;
    const size_t rowb = ((size_t)b * N_ + n) * QKV_;

#pragma unroll
    for (int part = 0; part < 2; ++part) {
        const int coff = part * 1024 + h * 128;
        unsigned short* dst = part == 0 ? Q : K;
#pragma unroll
        for (int jj = 0; jj < 4; ++jj) {
            const int d0 = (lg + jj * 4) * 8;
            short8 vv = *(const short8*)(qkv + rowb + coff + d0);
            unsigned short* pv = (unsigned short*)&vv;
            if (n != N_ - 1) {
#pragma unroll
                for (int p = 0; p < 4; ++p) {
                    int i0 = (d0 >> 1) + p;
                    float invf = exp2f(-(float)i0 * ROPE_C);
                    float th = (float)n * invf;
                    float cs = __cosf(th), sn = __sinf(th);
                    float e = bf2f(pv[2 * p]), o = bf2f(pv[2 * p + 1]);
                    pv[2 * p]     = f2bf(e * cs - o * sn);
                    pv[2 * p + 1] = f2bf(o * cs + e * sn);
                }
            }
            *(short8*)(dst + ((size_t)bh * N_ + n) * HEAD_ + d0) = vv;
        }
    }

#pragma unroll
    for (int jj = 0; jj < 4; ++jj) {
        const int d0 = (lg + jj * 4) * 8;
        short8 vv = *(const short8*)(qkv + rowb + 2048 + h * 128 + d0);
        unsigned short* pv = (unsigned short*)&vv;
#pragma unroll
        for (int j = 0; j < 8; ++j)
            lT[(d0 + j) * 65 + nn] = pv[j];
    }
    __syncthreads();
    {
        const int d = t >> 1, half = t & 1;
        unsigned short ob[32];
#pragma unroll
        for (int i = 0; i < 32; ++i)
            ob[i] = (unsigned short)lT[d * 65 + half * 32 + i];
        unsigned short* dst = Vt + ((size_t)bh * HEAD_ + d) * N_ + n0 + half * 32;
#pragma unroll
        for (int i = 0; i < 4; ++i)
            *(short8*)(dst + i * 8) = *(short8*)&ob[i * 8];
    }
}

// ---------------------------------------------------------------------------
// K3: flash attention, bf16 MFMA — ONLY change vs R4: fixed-shift softmax
// (exact by shift-invariance) + deferred row-sum reduction. Explicit
// lgkmcnt(0) + compiler barrier guards the lPw write->read round-trip.
// ---------------------------------------------------------------------------
__global__ __launch_bounds__(256) void k_attn(
    const unsigned short* __restrict__ Q, const unsigned short* __restrict__ K,
    const unsigned short* __restrict__ Vt, float* __restrict__ Op)
{
    __shared__ unsigned short lK[64 * 136];
    __shared__ unsigned short lV[128 * 72];
    __shared__ unsigned short lP[4 * 16 * 72];

    const int t = threadIdx.x;
    const int w = t >> 6, l = t & 63;
    const int lm = l & 15, quad = l >> 4;
    const int bid = blockIdx.x;
    const int bh = bid & 31;
    const int qt = bid >> 5;
    const int n0 = qt * 64;
    const unsigned short* Qb = Q  + (size_t)bh * N_ * HEAD_;
    const unsigned short* Kb = K  + (size_t)bh * N_ * HEAD_;
    const unsigned short* Vb = Vt + (size_t)bh * N_ * HEAD_;

    short8 aq[4];
    {
        const unsigned short* qp = Qb + ((size_t)(n0 + w * 16 + lm)) * 128 + quad * 8;
#pragma unroll
        for (int ks = 0; ks < 4; ++ks)
            aq[ks] = *(const short8*)(qp + ks * 32);
    }

    f32x4 Oa[8];
#pragma unroll
    for (int i = 0; i < 8; ++i) Oa[i] = (f32x4){0.f, 0.f, 0.f, 0.f};
    float ps[4] = {0.f, 0.f, 0.f, 0.f};
    const float C1 = SCALE_ * 1.44269504f;   // fold scale + log2(e)
    const float C0 = -23.08312f;             // -16*log2(e); any const shift is exact

    for (int jt = 0; jt < 32; ++jt) {
        __syncthreads();
#pragma unroll
        for (int i = 0; i < 4; ++i) {
            int c = t + 256 * i;
            int r = c >> 4, cc = c & 15;
            *(short8*)&lK[r * 136 + cc * 8] =
                *(const short8*)(Kb + ((size_t)(jt * 64 + r)) * 128 + cc * 8);
        }
#pragma unroll
        for (int i = 0; i < 4; ++i) {
            int c = t + 256 * i;
            int r = c >> 3, cc = c & 7;
            *(short8*)&lV[r * 72 + cc * 8] =
                *(const short8*)(Vb + (size_t)r * N_ + jt * 64 + cc * 8);
        }
        __syncthreads();

        f32x4 S[4];
#pragma unroll
        for (int nb = 0; nb < 4; ++nb) {
            S[nb] = (f32x4){0.f, 0.f, 0.f, 0.f};
#pragma unroll
            for (int ks = 0; ks < 4; ++ks) {
                short8 bk = *(short8*)&lK[(nb * 16 + lm) * 136 + ks * 32 + quad * 8];
                S[nb] = __builtin_amdgcn_mfma_f32_16x16x32_bf16(aq[ks], bk, S[nb], 0, 0, 0);
            }
        }

        // p = exp(logit - 16): one fma + one v_exp_f32 per element
        unsigned short pb[4][4];
#pragma unroll
        for (int nb = 0; nb < 4; ++nb)
#pragma unroll
            for (int r = 0; r < 4; ++r) {
                float p = exp2f(S[nb][r] * C1 + C0);
                ps[r] += p;
                pb[nb][r] = f2bf(p);
            }

        // P (C/D layout) -> wave-private LDS -> A-operand layout
        unsigned short* lPw = &lP[w * 16 * 72];
#pragma unroll
        for (int nb = 0; nb < 4; ++nb)
#pragma unroll
            for (int r = 0; r < 4; ++r)
                lPw[(quad * 4 + r) * 72 + nb * 16 + lm] = pb[nb][r];
        // ensure the writes above complete (and are not reordered) before reads
        asm volatile("s_waitcnt lgkmcnt(0)" ::: "memory");

#pragma unroll
        for (int ks2 = 0; ks2 < 2; ++ks2) {
            short8 ap = *(short8*)&lPw[lm * 72 + ks2 * 32 + quad * 8];
#pragma unroll
            for (int nb8 = 0; nb8 < 8; ++nb8) {
                short8 bv = *(short8*)&lV[(nb8 * 16 + lm) * 72 + ks2 * 32 + quad * 8];
                Oa[nb8] = __builtin_amdgcn_mfma_f32_16x16x32_bf16(ap, bv, Oa[nb8], 0, 0, 0);
            }
        }
    }

    // one-time row-sum reduction across the 16 lanes of each quad
#pragma unroll
    for (int off = 1; off <= 8; off <<= 1)
#pragma unroll
        for (int r = 0; r < 4; ++r) ps[r] += __shfl_xor(ps[r], off);

    const int b = bh >> 3, h = bh & 7;
#pragma unroll
    for (int r = 0; r < 4; ++r) {
        float il = 1.f / ps[r];
        int n = n0 + w * 16 + quad * 4 + r;
        float* op = Op + ((size_t)b * N_ + n) * INNER_ + h * HEAD_ + lm;
#pragma unroll
        for (int nb8 = 0; nb8 < 8; ++nb8)
            op[nb8 * 16] = Oa[nb8][r] * il;
    }
}

// ---------------------------------------------------------------------------
// K4: output projection out[8192,128] = O[8192,1024] @ w_out^T + b_out (fp32)
// ---------------------------------------------------------------------------
__global__ __launch_bounds__(256) void k_proj(
    const float* __restrict__ O, const float* __restrict__ w,
    const float* __restrict__ bias, float* __restrict__ out)
{
    __shared__ float Ot[64 * 128];
    __shared__ float wt[64 * 128];
    const int t = threadIdx.x;
    const int row0 = blockIdx.x * 64;
    const int e0   = blockIdx.y * 64;
    const int tx = t & 15, ty = t >> 4;
    float acc[4][4] = {};
    for (int kt = 0; kt < 8; ++kt) {
        __syncthreads();
#pragma unroll
        for (int i = 0; i < 8; ++i) {
            int f = t + 256 * i;  int r = f >> 5, c4 = f & 31;
            *(float4*)&Ot[r * 128 + c4 * 4] =
                *(const float4*)(O + (size_t)(row0 + r) * 1024 + kt * 128 + c4 * 4);
            float4 w4 = *(const float4*)(w + (size_t)(e0 + r) * 1024 + kt * 128 + c4 * 4);
            int pc = c4 ^ ((r >> 2) & 7);
            *(float4*)&wt[r * 128 + pc * 4] = w4;
        }
        __syncthreads();
#pragma unroll
        for (int c4 = 0; c4 < 32; ++c4) {
            int pc = c4 ^ (tx & 7);
            float4 wv[4], xv[4];
#pragma unroll
            for (int k = 0; k < 4; ++k)
                wv[k] = *(float4*)&wt[(tx * 4 + k) * 128 + pc * 4];
#pragma unroll
            for (int rr = 0; rr < 4; ++rr)
                xv[rr] = *(float4*)&Ot[(ty * 4 + rr) * 128 + c4 * 4];
#pragma unroll
            for (int rr = 0; rr < 4; ++rr)
#pragma unroll
                for (int k = 0; k < 4; ++k)
                    acc[rr][k] += xv[rr].x * wv[k].x + xv[rr].y * wv[k].y
                                + xv[rr].z * wv[k].z + xv[rr].w * wv[k].w;
        }
    }
    float4 b4 = *(const float4*)(bias + e0 + tx * 4);
#pragma unroll
    for (int rr = 0; rr < 4; ++rr) {
        int rg = row0 + ty * 4 + rr;
        float4 o4;
        o4.x = acc[rr][0] + b4.x; o4.y = acc[rr][1] + b4.y;
        o4.z = acc[rr][2] + b4.z; o4.w = acc[rr][3] + b4.w;
        *(float4*)(out + (size_t)rg * 128 + e0 + tx * 4) = o4;
    }
}

// ---------------------------------------------------------------------------
extern "C" void kernel_launch(void* const* d_in, const int* in_sizes, int n_in,
                              void* d_out, int out_size, void* d_ws, size_t ws_size,
                              hipStream_t stream) {
    const float* x      = (const float*)d_in[0];
    const float* gamma  = (const float*)d_in[1];
    const float* beta   = (const float*)d_in[2];
    const float* w_qkv  = (const float*)d_in[3];
    const float* w_out  = (const float*)d_in[4];
    const float* b_out  = (const float*)d_in[5];
    float* out = (float*)d_out;
    char* wsb = (char*)d_ws;
    unsigned short* Q   = (unsigned short*)(wsb);
    unsigned short* K   = (unsigned short*)(wsb + (16ull << 20));
    unsigned short* Vt  = (unsigned short*)(wsb + (32ull << 20));
    unsigned short* qkv = (unsigned short*)(wsb + (48ull << 20));
    float* xn           = (float*)(wsb + (96ull << 20));
    float* O            = (float*)(wsb + (48ull << 20));   // reuses qkv region

    k_ln       <<<dim3(2048),    256, 0, stream>>>(x, gamma, beta, xn);
    k_qkv_gemm <<<dim3(128, 24), 256, 0, stream>>>(xn, w_qkv, qkv);
    k_rope     <<<dim3(32, 32),  256, 0, stream>>>(qkv, Q, K, Vt);
    k_attn     <<<dim3(1024),    256, 0, stream>>>(Q, K, Vt, O);
    k_proj     <<<dim3(128, 2),  256, 0, stream>>>(O, w_out, b_out, out);
}

// Round 8
// 325.927 us; speedup vs baseline: 14.3610x; 1.3553x over previous
//
#include <hip/hip_runtime.h>
#include <hip/hip_bf16.h>
#include <hip/hip_fp16.h>

// Problem constants
#define B_      4
#define N_      2048
#define DIM_    128
#define HEADS_  8
#define HEAD_   128
#define INNER_  1024
#define QKV_    3072
#define EPS_    1e-5f
#define SCALE_  0.08838834764831845f   // HEAD^-0.5
// log2(10000)/64 for rope inv_freq = 2^(-i * this)
#define ROPE_C  0.20762050593046015f

typedef __attribute__((ext_vector_type(8))) short short8;   // 8 bf16 = 4 VGPRs
typedef __attribute__((ext_vector_type(4))) float f32x4;    // MFMA C/D

// Workspace (byte offsets) — R4 layout:
//  Q   [0,16M)  K [16M,32M)  Vt [32M,48M)   (bf16)
//  qkv [48M,96M) bf16 [8192][3072] -- dead after k_rope; O fp32 reuses [48M,80M)
//  xn  [96M,100M) fp32 [8192][128]

__device__ __forceinline__ unsigned short f2bf(float f) {
    unsigned u = __builtin_bit_cast(unsigned, f);
    u = (u + 0x7fffu + ((u >> 16) & 1u)) >> 16;
    return (unsigned short)u;
}
__device__ __forceinline__ float bf2f(unsigned short h) {
    unsigned u = ((unsigned)h) << 16;
    return __builtin_bit_cast(float, u);
}
__device__ __forceinline__ unsigned pk2(float a, float b) {
    return (unsigned)f2bf(a) | ((unsigned)f2bf(b) << 16);
}

// ---------------------------------------------------------------------------
// K0: LayerNorm -> fp32 xn. One wave per row, lane holds 2 elems.
// ---------------------------------------------------------------------------
__global__ __launch_bounds__(256) void k_ln(
    const float* __restrict__ x, const float* __restrict__ g,
    const float* __restrict__ be, float* __restrict__ xn)
{
    const int w = threadIdx.x >> 6, l = threadIdx.x & 63;
    const int row = blockIdx.x * 4 + w;
    float2 v = *(const float2*)(x + (size_t)row * 128 + l * 2);
    float s = v.x + v.y, s2 = v.x * v.x + v.y * v.y;
#pragma unroll
    for (int off = 1; off < 64; off <<= 1) {
        s  += __shfl_xor(s, off);
        s2 += __shfl_xor(s2, off);
    }
    float mu = s * (1.f / 128.f);
    float var = s2 * (1.f / 128.f) - mu * mu;
    float rs = rsqrtf(var + EPS_);
    float2 gg = *(const float2*)(g + l * 2);
    float2 bb = *(const float2*)(be + l * 2);
    float2 o;
    o.x = (v.x - mu) * rs * gg.x + bb.x;
    o.y = (v.y - mu) * rs * gg.y + bb.y;
    *(float2*)(xn + (size_t)row * 128 + l * 2) = o;
}

// ---------------------------------------------------------------------------
// K1: QKV GEMM, bf16 MFMA 16x16x32 -> qkv buffer (R4-validated version)
// ---------------------------------------------------------------------------
__global__ __launch_bounds__(256) void k_qkv_gemm(
    const float* __restrict__ xn, const float* __restrict__ w,
    unsigned short* __restrict__ qkv)
{
    __shared__ unsigned short lA[64 * 136];
    __shared__ unsigned short lB[128 * 136];
    const int t = threadIdx.x;
    const int wv = t >> 6, l = t & 63;
    const int lm = l & 15, quad = l >> 4;
    const int row0 = blockIdx.x * 64;
    const int e0   = blockIdx.y * 128;

#pragma unroll
    for (int i = 0; i < 4; ++i) {
        int c = t + 256 * i;  int r = c >> 4, c8 = c & 15;
        const float* src = xn + (size_t)(row0 + r) * 128 + c8 * 8;
        float4 f0 = *(const float4*)src, f1 = *(const float4*)(src + 4);
        uint4 u = { pk2(f0.x, f0.y), pk2(f0.z, f0.w), pk2(f1.x, f1.y), pk2(f1.z, f1.w) };
        *(uint4*)&lA[r * 136 + c8 * 8] = u;
    }
#pragma unroll
    for (int i = 0; i < 8; ++i) {
        int c = t + 256 * i;  int r = c >> 4, c8 = c & 15;
        const float* src = w + (size_t)(e0 + r) * 128 + c8 * 8;
        float4 f0 = *(const float4*)src, f1 = *(const float4*)(src + 4);
        uint4 u = { pk2(f0.x, f0.y), pk2(f0.z, f0.w), pk2(f1.x, f1.y), pk2(f1.z, f1.w) };
        *(uint4*)&lB[r * 136 + c8 * 8] = u;
    }
    __syncthreads();

    short8 af[4];
#pragma unroll
    for (int ks = 0; ks < 4; ++ks)
        af[ks] = *(short8*)&lA[(wv * 16 + lm) * 136 + ks * 32 + quad * 8];

    f32x4 acc[8];
#pragma unroll
    for (int ct = 0; ct < 8; ++ct) acc[ct] = (f32x4){0.f, 0.f, 0.f, 0.f};
#pragma unroll
    for (int ks = 0; ks < 4; ++ks) {
        short8 a = af[ks];
#pragma unroll
        for (int ct = 0; ct < 8; ++ct) {
            short8 b = *(short8*)&lB[(ct * 16 + lm) * 136 + ks * 32 + quad * 8];
            acc[ct] = __builtin_amdgcn_mfma_f32_16x16x32_bf16(a, b, acc[ct], 0, 0, 0);
        }
    }
    __syncthreads();

#pragma unroll
    for (int ct = 0; ct < 8; ++ct)
#pragma unroll
        for (int r = 0; r < 4; ++r)
            lA[(wv * 16 + quad * 4 + r) * 136 + ct * 16 + lm] = f2bf(acc[ct][r]);
    __syncthreads();
#pragma unroll
    for (int i = 0; i < 4; ++i) {
        int c = t + 256 * i;  int r = c >> 4, c8 = c & 15;
        *(uint4*)(qkv + (size_t)(row0 + r) * QKV_ + e0 + c8 * 8) =
            *(uint4*)&lA[r * 136 + c8 * 8];
    }
}

// ---------------------------------------------------------------------------
// K2: rope Q,K (all heads, n < N-1) + scatter; V -> Vt transpose via LDS.
// (R4-validated version)
// ---------------------------------------------------------------------------
__global__ __launch_bounds__(256) void k_rope(
    const unsigned short* __restrict__ qkv, unsigned short* __restrict__ Q,
    unsigned short* __restrict__ K, unsigned short* __restrict__ Vt)
{
    __shared__ unsigned lT[128 * 65];
    const int t = threadIdx.x;
    const int bh = blockIdx.x;
    const int n0 = blockIdx.y * 64;
    const int b = bh >> 3, h = bh & 7;
    const int nn = t >> 2, lg = t & 3;
    const int n = n0 + nn;
    const size_t rowb = ((size_t)b * N_ + n) * QKV_;

#pragma unroll
    for (int part = 0; part < 2; ++part) {
        const int coff = part * 1024 + h * 128;
        unsigned short* dst = part == 0 ? Q : K;
#pragma unroll
        for (int jj = 0; jj < 4; ++jj) {
            const int d0 = (lg + jj * 4) * 8;
            short8 vv = *(const short8*)(qkv + rowb + coff + d0);
            unsigned short* pv = (unsigned short*)&vv;
            if (n != N_ - 1) {
#pragma unroll
                for (int p = 0; p < 4; ++p) {
                    int i0 = (d0 >> 1) + p;
                    float invf = exp2f(-(float)i0 * ROPE_C);
                    float th = (float)n * invf;
                    float cs = __cosf(th), sn = __sinf(th);
                    float e = bf2f(pv[2 * p]), o = bf2f(pv[2 * p + 1]);
                    pv[2 * p]     = f2bf(e * cs - o * sn);
                    pv[2 * p + 1] = f2bf(o * cs + e * sn);
                }
            }
            *(short8*)(dst + ((size_t)bh * N_ + n) * HEAD_ + d0) = vv;
        }
    }

#pragma unroll
    for (int jj = 0; jj < 4; ++jj) {
        const int d0 = (lg + jj * 4) * 8;
        short8 vv = *(const short8*)(qkv + rowb + 2048 + h * 128 + d0);
        unsigned short* pv = (unsigned short*)&vv;
#pragma unroll
        for (int j = 0; j < 8; ++j)
            lT[(d0 + j) * 65 + nn] = pv[j];
    }
    __syncthreads();
    {
        const int d = t >> 1, half = t & 1;
        unsigned short ob[32];
#pragma unroll
        for (int i = 0; i < 32; ++i)
            ob[i] = (unsigned short)lT[d * 65 + half * 32 + i];
        unsigned short* dst = Vt + ((size_t)bh * HEAD_ + d) * N_ + n0 + half * 32;
#pragma unroll
        for (int i = 0; i < 4; ++i)
            *(short8*)(dst + i * 8) = *(short8*)&ob[i * 8];
    }
}

// ---------------------------------------------------------------------------
// K3: flash attention, bf16 MFMA, fixed-shift softmax.
// R8: (a) register-prefetch double-buffer — tile jt+1's global loads issue
// before compute of jt and stay in flight across the whole compute phase;
// (b) 2 q-tiles per wave (block = 128 q-rows, grid 512): every lK/lV b128
// read feeds TWO MFMAs. LDS 53KB -> 2 blocks/CU = grid parallelism.
// ---------------------------------------------------------------------------
__global__ __launch_bounds__(256) void k_attn(
    const unsigned short* __restrict__ Q, const unsigned short* __restrict__ K,
    const unsigned short* __restrict__ Vt, float* __restrict__ Op)
{
    __shared__ unsigned short lK[64 * 136];
    __shared__ unsigned short lV[128 * 72];
    __shared__ unsigned short lP[4 * 2 * 16 * 72];

    const int t = threadIdx.x;
    const int w = t >> 6, l = t & 63;
    const int lm = l & 15, quad = l >> 4;
    const int bid = blockIdx.x;
    const int bh = bid & 31;
    const int qt = bid >> 5;          // 0..15
    const int n0 = qt * 128;
    const unsigned short* Qb = Q  + (size_t)bh * N_ * HEAD_;
    const unsigned short* Kb = K  + (size_t)bh * N_ * HEAD_;
    const unsigned short* Vb = Vt + (size_t)bh * N_ * HEAD_;

    // persistent Q A-fragments for both q-tiles
    short8 aq[2][4];
#pragma unroll
    for (int tt = 0; tt < 2; ++tt) {
        const unsigned short* qp =
            Qb + ((size_t)(n0 + tt * 64 + w * 16 + lm)) * 128 + quad * 8;
#pragma unroll
        for (int ks = 0; ks < 4; ++ks)
            aq[tt][ks] = *(const short8*)(qp + ks * 32);
    }

    f32x4 Oa[2][8];
#pragma unroll
    for (int tt = 0; tt < 2; ++tt)
#pragma unroll
        for (int i = 0; i < 8; ++i) Oa[tt][i] = (f32x4){0.f, 0.f, 0.f, 0.f};
    float ps[2][4] = {{0.f,0.f,0.f,0.f},{0.f,0.f,0.f,0.f}};
    const float C1 = SCALE_ * 1.44269504f;
    const float C0 = -23.08312f;        // -16*log2(e); const shift is exact

    // prefetch registers for K tile (64x128) and V tile (128x64)
    short8 kr[4], vr[4];
#pragma unroll
    for (int i = 0; i < 4; ++i) {
        int c = t + 256 * i;
        kr[i] = *(const short8*)(Kb + ((size_t)(c >> 4)) * 128 + (c & 15) * 8);
        vr[i] = *(const short8*)(Vb + (size_t)(c >> 3) * N_ + (c & 7) * 8);
    }

    unsigned short* lPw = &lP[w * 2 * 16 * 72];

    for (int jt = 0; jt < 32; ++jt) {
        __syncthreads();
        // commit prefetch to LDS
#pragma unroll
        for (int i = 0; i < 4; ++i) {
            int c = t + 256 * i;
            *(short8*)&lK[(c >> 4) * 136 + (c & 15) * 8] = kr[i];
            *(short8*)&lV[(c >> 3) * 72  + (c & 7)  * 8] = vr[i];
        }
        __syncthreads();
        // issue next tile's loads; they complete during compute below
        if (jt < 31) {
#pragma unroll
            for (int i = 0; i < 4; ++i) {
                int c = t + 256 * i;
                kr[i] = *(const short8*)(Kb + ((size_t)((jt + 1) * 64 + (c >> 4))) * 128 + (c & 15) * 8);
                vr[i] = *(const short8*)(Vb + (size_t)(c >> 3) * N_ + (jt + 1) * 64 + (c & 7) * 8);
            }
        }

        // S = Q K^T for both q-tiles; each bk read feeds 2 MFMAs
        f32x4 S0[4], S1[4];
#pragma unroll
        for (int nb = 0; nb < 4; ++nb) {
            S0[nb] = (f32x4){0.f, 0.f, 0.f, 0.f};
            S1[nb] = (f32x4){0.f, 0.f, 0.f, 0.f};
#pragma unroll
            for (int ks = 0; ks < 4; ++ks) {
                short8 bk = *(short8*)&lK[(nb * 16 + lm) * 136 + ks * 32 + quad * 8];
                S0[nb] = __builtin_amdgcn_mfma_f32_16x16x32_bf16(aq[0][ks], bk, S0[nb], 0, 0, 0);
                S1[nb] = __builtin_amdgcn_mfma_f32_16x16x32_bf16(aq[1][ks], bk, S1[nb], 0, 0, 0);
            }
        }

        // p = exp(logit - 16)
        unsigned short pb0[4][4], pb1[4][4];
#pragma unroll
        for (int nb = 0; nb < 4; ++nb)
#pragma unroll
            for (int r = 0; r < 4; ++r) {
                float p0 = exp2f(S0[nb][r] * C1 + C0);
                float p1 = exp2f(S1[nb][r] * C1 + C0);
                ps[0][r] += p0;  ps[1][r] += p1;
                pb0[nb][r] = f2bf(p0);  pb1[nb][r] = f2bf(p1);
            }

        // P (C/D layout) -> wave-private LDS halves -> A-operand layout
#pragma unroll
        for (int nb = 0; nb < 4; ++nb)
#pragma unroll
            for (int r = 0; r < 4; ++r) {
                lPw[(quad * 4 + r) * 72 + nb * 16 + lm] = pb0[nb][r];
                lPw[1152 + (quad * 4 + r) * 72 + nb * 16 + lm] = pb1[nb][r];
            }
        asm volatile("s_waitcnt lgkmcnt(0)" ::: "memory");

        // O += P V; each bv read feeds 2 MFMAs
#pragma unroll
        for (int ks2 = 0; ks2 < 2; ++ks2) {
            short8 ap0 = *(short8*)&lPw[lm * 72 + ks2 * 32 + quad * 8];
            short8 ap1 = *(short8*)&lPw[1152 + lm * 72 + ks2 * 32 + quad * 8];
#pragma unroll
            for (int nb8 = 0; nb8 < 8; ++nb8) {
                short8 bv = *(short8*)&lV[(nb8 * 16 + lm) * 72 + ks2 * 32 + quad * 8];
                Oa[0][nb8] = __builtin_amdgcn_mfma_f32_16x16x32_bf16(ap0, bv, Oa[0][nb8], 0, 0, 0);
                Oa[1][nb8] = __builtin_amdgcn_mfma_f32_16x16x32_bf16(ap1, bv, Oa[1][nb8], 0, 0, 0);
            }
        }
    }

    // one-time row-sum reduction across the 16 lanes of each quad
#pragma unroll
    for (int off = 1; off <= 8; off <<= 1)
#pragma unroll
        for (int tt = 0; tt < 2; ++tt)
#pragma unroll
            for (int r = 0; r < 4; ++r) ps[tt][r] += __shfl_xor(ps[tt][r], off);

    const int b = bh >> 3, h = bh & 7;
#pragma unroll
    for (int tt = 0; tt < 2; ++tt)
#pragma unroll
        for (int r = 0; r < 4; ++r) {
            float il = 1.f / ps[tt][r];
            int n = n0 + tt * 64 + w * 16 + quad * 4 + r;
            float* op = Op + ((size_t)b * N_ + n) * INNER_ + h * HEAD_ + lm;
#pragma unroll
            for (int nb8 = 0; nb8 < 8; ++nb8)
                op[nb8 * 16] = Oa[tt][nb8][r] * il;
        }
}

// ---------------------------------------------------------------------------
// K4: output projection out[8192,128] = O[8192,1024] @ w_out^T + b_out (fp32)
// ---------------------------------------------------------------------------
__global__ __launch_bounds__(256) void k_proj(
    const float* __restrict__ O, const float* __restrict__ w,
    const float* __restrict__ bias, float* __restrict__ out)
{
    __shared__ float Ot[64 * 128];
    __shared__ float wt[64 * 128];
    const int t = threadIdx.x;
    const int row0 = blockIdx.x * 64;
    const int e0   = blockIdx.y * 64;
    const int tx = t & 15, ty = t >> 4;
    float acc[4][4] = {};
    for (int kt = 0; kt < 8; ++kt) {
        __syncthreads();
#pragma unroll
        for (int i = 0; i < 8; ++i) {
            int f = t + 256 * i;  int r = f >> 5, c4 = f & 31;
            *(float4*)&Ot[r * 128 + c4 * 4] =
                *(const float4*)(O + (size_t)(row0 + r) * 1024 + kt * 128 + c4 * 4);
            float4 w4 = *(const float4*)(w + (size_t)(e0 + r) * 1024 + kt * 128 + c4 * 4);
            int pc = c4 ^ ((r >> 2) & 7);
            *(float4*)&wt[r * 128 + pc * 4] = w4;
        }
        __syncthreads();
#pragma unroll
        for (int c4 = 0; c4 < 32; ++c4) {
            int pc = c4 ^ (tx & 7);
            float4 wv[4], xv[4];
#pragma unroll
            for (int k = 0; k < 4; ++k)
                wv[k] = *(float4*)&wt[(tx * 4 + k) * 128 + pc * 4];
#pragma unroll
            for (int rr = 0; rr < 4; ++rr)
                xv[rr] = *(float4*)&Ot[(ty * 4 + rr) * 128 + c4 * 4];
#pragma unroll
            for (int rr = 0; rr < 4; ++rr)
#pragma unroll
                for (int k = 0; k < 4; ++k)
                    acc[rr][k] += xv[rr].x * wv[k].x + xv[rr].y * wv[k].y
                                + xv[rr].z * wv[k].z + xv[rr].w * wv[k].w;
        }
    }
    float4 b4 = *(const float4*)(bias + e0 + tx * 4);
#pragma unroll
    for (int rr = 0; rr < 4; ++rr) {
        int rg = row0 + ty * 4 + rr;
        float4 o4;
        o4.x = acc[rr][0] + b4.x; o4.y = acc[rr][1] + b4.y;
        o4.z = acc[rr][2] + b4.z; o4.w = acc[rr][3] + b4.w;
        *(float4*)(out + (size_t)rg * 128 + e0 + tx * 4) = o4;
    }
}

// ---------------------------------------------------------------------------
extern "C" void kernel_launch(void* const* d_in, const int* in_sizes, int n_in,
                              void* d_out, int out_size, void* d_ws, size_t ws_size,
                              hipStream_t stream) {
    const float* x      = (const float*)d_in[0];
    const float* gamma  = (const float*)d_in[1];
    const float* beta   = (const float*)d_in[2];
    const float* w_qkv  = (const float*)d_in[3];
    const float* w_out  = (const float*)d_in[4];
    const float* b_out  = (const float*)d_in[5];
    float* out = (float*)d_out;
    char* wsb = (char*)d_ws;
    unsigned short* Q   = (unsigned short*)(wsb);
    unsigned short* K   = (unsigned short*)(wsb + (16ull << 20));
    unsigned short* Vt  = (unsigned short*)(wsb + (32ull << 20));
    unsigned short* qkv = (unsigned short*)(wsb + (48ull << 20));
    float* xn           = (float*)(wsb + (96ull << 20));
    float* O            = (float*)(wsb + (48ull << 20));   // reuses qkv region

    k_ln       <<<dim3(2048),    256, 0, stream>>>(x, gamma, beta, xn);
    k_qkv_gemm <<<dim3(128, 24), 256, 0, stream>>>(xn, w_qkv, qkv);
    k_rope     <<<dim3(32, 32),  256, 0, stream>>>(qkv, Q, K, Vt);
    k_attn     <<<dim3(512),     256, 0, stream>>>(Q, K, Vt, O);
    k_proj     <<<dim3(128, 2),  256, 0, stream>>>(O, w_out, b_out, out);
}

// Round 9
// 243.467 us; speedup vs baseline: 19.2249x; 1.3387x over previous
//
#include <hip/hip_runtime.h>
#include <hip/hip_bf16.h>
#include <hip/hip_fp16.h>

// Problem constants
#define B_      4
#define N_      2048
#define DIM_    128
#define HEADS_  8
#define HEAD_   128
#define INNER_  1024
#define QKV_    3072
#define EPS_    1e-5f
#define SCALE_  0.08838834764831845f   // HEAD^-0.5
// log2(10000)/64 for rope inv_freq = 2^(-i * this)
#define ROPE_C  0.20762050593046015f

typedef __attribute__((ext_vector_type(8))) short short8;   // 8 bf16 = 4 VGPRs
typedef __attribute__((ext_vector_type(4))) float f32x4;    // MFMA C/D

// Workspace (byte offsets):
//  Q    [0,16M)   K [16M,32M)   Vt [32M,48M)        (bf16)
//  qkv  [48M,96M) bf16 [8192][3072]  -- dead after k_rope
//  Ob   [48M,64M) bf16 [B][N][INNER] -- written by k_attn after qkv dies
//  xnb  [96M,98M) bf16 [8192][128]
//  wqb  [98M,98.75M) bf16 [3072][128]
//  wob  [99M,99.25M) bf16 [128][1024]

__device__ __forceinline__ unsigned short f2bf(float f) {
    unsigned u = __builtin_bit_cast(unsigned, f);
    u = (u + 0x7fffu + ((u >> 16) & 1u)) >> 16;
    return (unsigned short)u;
}
__device__ __forceinline__ float bf2f(unsigned short h) {
    unsigned u = ((unsigned)h) << 16;
    return __builtin_bit_cast(float, u);
}
__device__ __forceinline__ unsigned pk2(float a, float b) {
    return (unsigned)f2bf(a) | ((unsigned)f2bf(b) << 16);
}

// ---------------------------------------------------------------------------
// K0: LayerNorm -> bf16 xnb. One wave per row, lane holds 2 elems.
// ---------------------------------------------------------------------------
__global__ __launch_bounds__(256) void k_ln(
    const float* __restrict__ x, const float* __restrict__ g,
    const float* __restrict__ be, unsigned short* __restrict__ xnb)
{
    const int w = threadIdx.x >> 6, l = threadIdx.x & 63;
    const int row = blockIdx.x * 4 + w;
    float2 v = *(const float2*)(x + (size_t)row * 128 + l * 2);
    float s = v.x + v.y, s2 = v.x * v.x + v.y * v.y;
#pragma unroll
    for (int off = 1; off < 64; off <<= 1) {
        s  += __shfl_xor(s, off);
        s2 += __shfl_xor(s2, off);
    }
    float mu = s * (1.f / 128.f);
    float var = s2 * (1.f / 128.f) - mu * mu;
    float rs = rsqrtf(var + EPS_);
    float2 gg = *(const float2*)(g + l * 2);
    float2 bb = *(const float2*)(be + l * 2);
    float ox = (v.x - mu) * rs * gg.x + bb.x;
    float oy = (v.y - mu) * rs * gg.y + bb.y;
    *(unsigned*)(xnb + (size_t)row * 128 + l * 2) = pk2(ox, oy);
}

// ---------------------------------------------------------------------------
// K0b: fp32 -> bf16 convert (grid-stride-free exact launch, 8 elems/thread)
// ---------------------------------------------------------------------------
__global__ __launch_bounds__(256) void k_cvt(
    const float* __restrict__ src, unsigned short* __restrict__ dst)
{
    size_t i = ((size_t)blockIdx.x * 256 + threadIdx.x) * 8;
    float4 f0 = *(const float4*)(src + i), f1 = *(const float4*)(src + i + 4);
    uint4 u = { pk2(f0.x, f0.y), pk2(f0.z, f0.w), pk2(f1.x, f1.y), pk2(f1.z, f1.w) };
    *(uint4*)(dst + i) = u;
}

// ---------------------------------------------------------------------------
// K1: QKV GEMM, bf16-native. M=128 x N=128, K=128 one-shot. Grid (64, 24).
// Stage = pure uint4 copies; B tile amortized over 128 rows; 64 MFMA/wave.
// LDS 2x 128x136 bf16 = 68KB -> 2 blocks/CU.
// ---------------------------------------------------------------------------
__global__ __launch_bounds__(256) void k_qkv_gemm(
    const unsigned short* __restrict__ xnb, const unsigned short* __restrict__ wb,
    unsigned short* __restrict__ qkv)
{
    __shared__ unsigned short lA[128 * 136];
    __shared__ unsigned short lB[128 * 136];
    const int t = threadIdx.x;
    const int wv = t >> 6, l = t & 63;
    const int lm = l & 15, quad = l >> 4;
    const int row0 = blockIdx.x * 128;
    const int e0   = blockIdx.y * 128;

#pragma unroll
    for (int i = 0; i < 8; ++i) {
        int c = t + 256 * i;  int r = c >> 4, c8 = c & 15;
        *(uint4*)&lA[r * 136 + c8 * 8] =
            *(const uint4*)(xnb + (size_t)(row0 + r) * 128 + c8 * 8);
        *(uint4*)&lB[r * 136 + c8 * 8] =
            *(const uint4*)(wb + (size_t)(e0 + r) * 128 + c8 * 8);
    }
    __syncthreads();

    short8 af[2][4];
#pragma unroll
    for (int mt = 0; mt < 2; ++mt)
#pragma unroll
        for (int ks = 0; ks < 4; ++ks)
            af[mt][ks] = *(short8*)&lA[(wv * 32 + mt * 16 + lm) * 136 + ks * 32 + quad * 8];

    f32x4 acc[2][8];
#pragma unroll
    for (int mt = 0; mt < 2; ++mt)
#pragma unroll
        for (int ct = 0; ct < 8; ++ct) acc[mt][ct] = (f32x4){0.f, 0.f, 0.f, 0.f};
#pragma unroll
    for (int ks = 0; ks < 4; ++ks) {
#pragma unroll
        for (int ct = 0; ct < 8; ++ct) {
            short8 b = *(short8*)&lB[(ct * 16 + lm) * 136 + ks * 32 + quad * 8];
            acc[0][ct] = __builtin_amdgcn_mfma_f32_16x16x32_bf16(af[0][ks], b, acc[0][ct], 0, 0, 0);
            acc[1][ct] = __builtin_amdgcn_mfma_f32_16x16x32_bf16(af[1][ks], b, acc[1][ct], 0, 0, 0);
        }
    }
    __syncthreads();

    // C (C/D layout) -> LDS (reuse lA) -> coalesced bf16 store
#pragma unroll
    for (int mt = 0; mt < 2; ++mt)
#pragma unroll
        for (int ct = 0; ct < 8; ++ct)
#pragma unroll
            for (int r = 0; r < 4; ++r)
                lA[(wv * 32 + mt * 16 + quad * 4 + r) * 136 + ct * 16 + lm] =
                    f2bf(acc[mt][ct][r]);
    __syncthreads();
#pragma unroll
    for (int i = 0; i < 8; ++i) {
        int c = t + 256 * i;  int r = c >> 4, c8 = c & 15;
        *(uint4*)(qkv + (size_t)(row0 + r) * QKV_ + e0 + c8 * 8) =
            *(uint4*)&lA[r * 136 + c8 * 8];
    }
}

// ---------------------------------------------------------------------------
// K2: rope Q,K (all heads, n < N-1) + scatter; V -> Vt transpose via LDS.
// (R4-validated version, unchanged)
// ---------------------------------------------------------------------------
__global__ __launch_bounds__(256) void k_rope(
    const unsigned short* __restrict__ qkv, unsigned short* __restrict__ Q,
    unsigned short* __restrict__ K, unsigned short* __restrict__ Vt)
{
    __shared__ unsigned lT[128 * 65];
    const int t = threadIdx.x;
    const int bh = blockIdx.x;
    const int n0 = blockIdx.y * 64;
    const int b = bh >> 3, h = bh & 7;
    const int nn = t >> 2, lg = t & 3;
    const int n = n0 + nn;
    const size_t rowb = ((size_t)b * N_ + n) * QKV_;

#pragma unroll
    for (int part = 0; part < 2; ++part) {
        const int coff = part * 1024 + h * 128;
        unsigned short* dst = part == 0 ? Q : K;
#pragma unroll
        for (int jj = 0; jj < 4; ++jj) {
            const int d0 = (lg + jj * 4) * 8;
            short8 vv = *(const short8*)(qkv + rowb + coff + d0);
            unsigned short* pv = (unsigned short*)&vv;
            if (n != N_ - 1) {
#pragma unroll
                for (int p = 0; p < 4; ++p) {
                    int i0 = (d0 >> 1) + p;
                    float invf = exp2f(-(float)i0 * ROPE_C);
                    float th = (float)n * invf;
                    float cs = __cosf(th), sn = __sinf(th);
                    float e = bf2f(pv[2 * p]), o = bf2f(pv[2 * p + 1]);
                    pv[2 * p]     = f2bf(e * cs - o * sn);
                    pv[2 * p + 1] = f2bf(o * cs + e * sn);
                }
            }
            *(short8*)(dst + ((size_t)bh * N_ + n) * HEAD_ + d0) = vv;
        }
    }

#pragma unroll
    for (int jj = 0; jj < 4; ++jj) {
        const int d0 = (lg + jj * 4) * 8;
        short8 vv = *(const short8*)(qkv + rowb + 2048 + h * 128 + d0);
        unsigned short* pv = (unsigned short*)&vv;
#pragma unroll
        for (int j = 0; j < 8; ++j)
            lT[(d0 + j) * 65 + nn] = pv[j];
    }
    __syncthreads();
    {
        const int d = t >> 1, half = t & 1;
        unsigned short ob[32];
#pragma unroll
        for (int i = 0; i < 32; ++i)
            ob[i] = (unsigned short)lT[d * 65 + half * 32 + i];
        unsigned short* dst = Vt + ((size_t)bh * HEAD_ + d) * N_ + n0 + half * 32;
#pragma unroll
        for (int i = 0; i < 4; ++i)
            *(short8*)(dst + i * 8) = *(short8*)&ob[i * 8];
    }
}

// ---------------------------------------------------------------------------
// K3: flash attention (R8-validated core). Only change: O stored as bf16.
// ---------------------------------------------------------------------------
__global__ __launch_bounds__(256) void k_attn(
    const unsigned short* __restrict__ Q, const unsigned short* __restrict__ K,
    const unsigned short* __restrict__ Vt, unsigned short* __restrict__ Ob)
{
    __shared__ unsigned short lK[64 * 136];
    __shared__ unsigned short lV[128 * 72];
    __shared__ unsigned short lP[4 * 2 * 16 * 72];

    const int t = threadIdx.x;
    const int w = t >> 6, l = t & 63;
    const int lm = l & 15, quad = l >> 4;
    const int bid = blockIdx.x;
    const int bh = bid & 31;
    const int qt = bid >> 5;          // 0..15
    const int n0 = qt * 128;
    const unsigned short* Qb = Q  + (size_t)bh * N_ * HEAD_;
    const unsigned short* Kb = K  + (size_t)bh * N_ * HEAD_;
    const unsigned short* Vb = Vt + (size_t)bh * N_ * HEAD_;

    short8 aq[2][4];
#pragma unroll
    for (int tt = 0; tt < 2; ++tt) {
        const unsigned short* qp =
            Qb + ((size_t)(n0 + tt * 64 + w * 16 + lm)) * 128 + quad * 8;
#pragma unroll
        for (int ks = 0; ks < 4; ++ks)
            aq[tt][ks] = *(const short8*)(qp + ks * 32);
    }

    f32x4 Oa[2][8];
#pragma unroll
    for (int tt = 0; tt < 2; ++tt)
#pragma unroll
        for (int i = 0; i < 8; ++i) Oa[tt][i] = (f32x4){0.f, 0.f, 0.f, 0.f};
    float ps[2][4] = {{0.f,0.f,0.f,0.f},{0.f,0.f,0.f,0.f}};
    const float C1 = SCALE_ * 1.44269504f;
    const float C0 = -23.08312f;        // -16*log2(e); const shift is exact

    short8 kr[4], vr[4];
#pragma unroll
    for (int i = 0; i < 4; ++i) {
        int c = t + 256 * i;
        kr[i] = *(const short8*)(Kb + ((size_t)(c >> 4)) * 128 + (c & 15) * 8);
        vr[i] = *(const short8*)(Vb + (size_t)(c >> 3) * N_ + (c & 7) * 8);
    }

    unsigned short* lPw = &lP[w * 2 * 16 * 72];

    for (int jt = 0; jt < 32; ++jt) {
        __syncthreads();
#pragma unroll
        for (int i = 0; i < 4; ++i) {
            int c = t + 256 * i;
            *(short8*)&lK[(c >> 4) * 136 + (c & 15) * 8] = kr[i];
            *(short8*)&lV[(c >> 3) * 72  + (c & 7)  * 8] = vr[i];
        }
        __syncthreads();
        if (jt < 31) {
#pragma unroll
            for (int i = 0; i < 4; ++i) {
                int c = t + 256 * i;
                kr[i] = *(const short8*)(Kb + ((size_t)((jt + 1) * 64 + (c >> 4))) * 128 + (c & 15) * 8);
                vr[i] = *(const short8*)(Vb + (size_t)(c >> 3) * N_ + (jt + 1) * 64 + (c & 7) * 8);
            }
        }

        f32x4 S0[4], S1[4];
#pragma unroll
        for (int nb = 0; nb < 4; ++nb) {
            S0[nb] = (f32x4){0.f, 0.f, 0.f, 0.f};
            S1[nb] = (f32x4){0.f, 0.f, 0.f, 0.f};
#pragma unroll
            for (int ks = 0; ks < 4; ++ks) {
                short8 bk = *(short8*)&lK[(nb * 16 + lm) * 136 + ks * 32 + quad * 8];
                S0[nb] = __builtin_amdgcn_mfma_f32_16x16x32_bf16(aq[0][ks], bk, S0[nb], 0, 0, 0);
                S1[nb] = __builtin_amdgcn_mfma_f32_16x16x32_bf16(aq[1][ks], bk, S1[nb], 0, 0, 0);
            }
        }

        unsigned short pb0[4][4], pb1[4][4];
#pragma unroll
        for (int nb = 0; nb < 4; ++nb)
#pragma unroll
            for (int r = 0; r < 4; ++r) {
                float p0 = exp2f(S0[nb][r] * C1 + C0);
                float p1 = exp2f(S1[nb][r] * C1 + C0);
                ps[0][r] += p0;  ps[1][r] += p1;
                pb0[nb][r] = f2bf(p0);  pb1[nb][r] = f2bf(p1);
            }

#pragma unroll
        for (int nb = 0; nb < 4; ++nb)
#pragma unroll
            for (int r = 0; r < 4; ++r) {
                lPw[(quad * 4 + r) * 72 + nb * 16 + lm] = pb0[nb][r];
                lPw[1152 + (quad * 4 + r) * 72 + nb * 16 + lm] = pb1[nb][r];
            }
        asm volatile("s_waitcnt lgkmcnt(0)" ::: "memory");

#pragma unroll
        for (int ks2 = 0; ks2 < 2; ++ks2) {
            short8 ap0 = *(short8*)&lPw[lm * 72 + ks2 * 32 + quad * 8];
            short8 ap1 = *(short8*)&lPw[1152 + lm * 72 + ks2 * 32 + quad * 8];
#pragma unroll
            for (int nb8 = 0; nb8 < 8; ++nb8) {
                short8 bv = *(short8*)&lV[(nb8 * 16 + lm) * 72 + ks2 * 32 + quad * 8];
                Oa[0][nb8] = __builtin_amdgcn_mfma_f32_16x16x32_bf16(ap0, bv, Oa[0][nb8], 0, 0, 0);
                Oa[1][nb8] = __builtin_amdgcn_mfma_f32_16x16x32_bf16(ap1, bv, Oa[1][nb8], 0, 0, 0);
            }
        }
    }

#pragma unroll
    for (int off = 1; off <= 8; off <<= 1)
#pragma unroll
        for (int tt = 0; tt < 2; ++tt)
#pragma unroll
            for (int r = 0; r < 4; ++r) ps[tt][r] += __shfl_xor(ps[tt][r], off);

    const int b = bh >> 3, h = bh & 7;
#pragma unroll
    for (int tt = 0; tt < 2; ++tt)
#pragma unroll
        for (int r = 0; r < 4; ++r) {
            float il = 1.f / ps[tt][r];
            int n = n0 + tt * 64 + w * 16 + quad * 4 + r;
            unsigned short* op = Ob + ((size_t)b * N_ + n) * INNER_ + h * HEAD_ + lm;
#pragma unroll
            for (int nb8 = 0; nb8 < 8; ++nb8)
                op[nb8 * 16] = f2bf(Oa[tt][nb8][r] * il);
        }
}

// ---------------------------------------------------------------------------
// K4: output projection, bf16 MFMA. out[8192,128] = Ob @ wob^T + b_out.
// Block: M=64 x N=64, K=1024 in 8 chunks. Grid (128, 2) = 256 blocks.
// ---------------------------------------------------------------------------
__global__ __launch_bounds__(256) void k_proj(
    const unsigned short* __restrict__ Ob, const unsigned short* __restrict__ wob,
    const float* __restrict__ bias, float* __restrict__ out)
{
    __shared__ unsigned short lA[64 * 136];
    __shared__ unsigned short lB[64 * 136];
    float* lCf = (float*)lA;              // reused as fp32 C tile [64][68] = 17408B
    const int t = threadIdx.x;
    const int wv = t >> 6, l = t & 63;
    const int lm = l & 15, quad = l >> 4;
    const int row0 = blockIdx.x * 64;
    const int e0   = blockIdx.y * 64;

    f32x4 acc[4];
#pragma unroll
    for (int ct = 0; ct < 4; ++ct) acc[ct] = (f32x4){0.f, 0.f, 0.f, 0.f};

    for (int kt = 0; kt < 8; ++kt) {
        __syncthreads();
#pragma unroll
        for (int i = 0; i < 4; ++i) {
            int c = t + 256 * i;  int r = c >> 4, c8 = c & 15;
            *(uint4*)&lA[r * 136 + c8 * 8] =
                *(const uint4*)(Ob + (size_t)(row0 + r) * 1024 + kt * 128 + c8 * 8);
            *(uint4*)&lB[r * 136 + c8 * 8] =
                *(const uint4*)(wob + (size_t)(e0 + r) * 1024 + kt * 128 + c8 * 8);
        }
        __syncthreads();
        short8 a_[4];
#pragma unroll
        for (int ks = 0; ks < 4; ++ks)
            a_[ks] = *(short8*)&lA[(wv * 16 + lm) * 136 + ks * 32 + quad * 8];
#pragma unroll
        for (int ks = 0; ks < 4; ++ks)
#pragma unroll
            for (int ct = 0; ct < 4; ++ct) {
                short8 b = *(short8*)&lB[(ct * 16 + lm) * 136 + ks * 32 + quad * 8];
                acc[ct] = __builtin_amdgcn_mfma_f32_16x16x32_bf16(a_[ks], b, acc[ct], 0, 0, 0);
            }
    }
    __syncthreads();
#pragma unroll
    for (int ct = 0; ct < 4; ++ct)
#pragma unroll
        for (int r = 0; r < 4; ++r)
            lCf[(wv * 16 + quad * 4 + r) * 68 + ct * 16 + lm] = acc[ct][r];
    __syncthreads();
#pragma unroll
    for (int i = 0; i < 4; ++i) {
        int c = t + 256 * i;  int r = c >> 4, c4 = c & 15;
        float4 v = *(float4*)&lCf[r * 68 + c4 * 4];
        float4 b4 = *(const float4*)(bias + e0 + c4 * 4);
        v.x += b4.x; v.y += b4.y; v.z += b4.z; v.w += b4.w;
        *(float4*)(out + (size_t)(row0 + r) * 128 + e0 + c4 * 4) = v;
    }
}

// ---------------------------------------------------------------------------
extern "C" void kernel_launch(void* const* d_in, const int* in_sizes, int n_in,
                              void* d_out, int out_size, void* d_ws, size_t ws_size,
                              hipStream_t stream) {
    const float* x      = (const float*)d_in[0];
    const float* gamma  = (const float*)d_in[1];
    const float* beta   = (const float*)d_in[2];
    const float* w_qkv  = (const float*)d_in[3];
    const float* w_out  = (const float*)d_in[4];
    const float* b_out  = (const float*)d_in[5];
    float* out = (float*)d_out;
    char* wsb = (char*)d_ws;
    unsigned short* Q    = (unsigned short*)(wsb);
    unsigned short* K    = (unsigned short*)(wsb + (16ull << 20));
    unsigned short* Vt   = (unsigned short*)(wsb + (32ull << 20));
    unsigned short* qkv  = (unsigned short*)(wsb + (48ull << 20));
    unsigned short* Ob   = (unsigned short*)(wsb + (48ull << 20));  // after qkv dies
    unsigned short* xnb  = (unsigned short*)(wsb + (96ull << 20));
    unsigned short* wqb  = (unsigned short*)(wsb + (98ull << 20));
    unsigned short* wob  = (unsigned short*)(wsb + (99ull << 20));

    k_ln       <<<dim3(2048),    256, 0, stream>>>(x, gamma, beta, xnb);
    k_cvt      <<<dim3(192),     256, 0, stream>>>(w_qkv, wqb);   // 3072*128
    k_cvt      <<<dim3(64),      256, 0, stream>>>(w_out, wob);   // 128*1024
    k_qkv_gemm <<<dim3(64, 24),  256, 0, stream>>>(xnb, wqb, qkv);
    k_rope     <<<dim3(32, 32),  256, 0, stream>>>(qkv, Q, K, Vt);
    k_attn     <<<dim3(512),     256, 0, stream>>>(Q, K, Vt, Ob);
    k_proj     <<<dim3(128, 2),  256, 0, stream>>>(Ob, wob, b_out, out);
}

// Round 11
// 211.212 us; speedup vs baseline: 22.1608x; 1.1527x over previous
//
#include <hip/hip_runtime.h>
#include <hip/hip_bf16.h>
#include <hip/hip_fp16.h>

// Problem constants
#define B_      4
#define N_      2048
#define DIM_    128
#define HEADS_  8
#define HEAD_   128
#define INNER_  1024
#define QKV_    3072
#define EPS_    1e-5f
#define SCALE_  0.08838834764831845f   // HEAD^-0.5
// log2(10000)/64 for rope inv_freq = 2^(-i * this)
#define ROPE_C  0.20762050593046015f

typedef __attribute__((ext_vector_type(8))) short short8;   // 8 bf16 = 4 VGPRs
typedef __attribute__((ext_vector_type(4))) short short4v;  // 4 bf16 = 2 VGPRs
typedef __attribute__((ext_vector_type(4))) float f32x4;    // MFMA C/D

// Workspace (byte offsets):
//  Q    [0,16M)   K [16M,32M)   Vt [32M,48M)        (bf16)
//  qkv  [48M,96M) bf16 [8192][3072]  -- dead after k_rope
//  Ob   [48M,64M) bf16 [B][N][INNER] -- written by k_attn after qkv dies
//  xnb  [96M,98M) bf16 [8192][128]
//  wqb  [98M,98.75M) bf16 [3072][128]
//  wob  [99M,99.25M) bf16 [128][1024]

__device__ __forceinline__ unsigned short f2bf(float f) {
    unsigned u = __builtin_bit_cast(unsigned, f);
    u = (u + 0x7fffu + ((u >> 16) & 1u)) >> 16;
    return (unsigned short)u;
}
__device__ __forceinline__ float bf2f(unsigned short h) {
    unsigned u = ((unsigned)h) << 16;
    return __builtin_bit_cast(float, u);
}
__device__ __forceinline__ unsigned pk2(float a, float b) {
    return (unsigned)f2bf(a) | ((unsigned)f2bf(b) << 16);
}

// ---------------------------------------------------------------------------
// K0: LayerNorm -> bf16 xnb. One wave per row, lane holds 2 elems.
// ---------------------------------------------------------------------------
__global__ __launch_bounds__(256) void k_ln(
    const float* __restrict__ x, const float* __restrict__ g,
    const float* __restrict__ be, unsigned short* __restrict__ xnb)
{
    const int w = threadIdx.x >> 6, l = threadIdx.x & 63;
    const int row = blockIdx.x * 4 + w;
    float2 v = *(const float2*)(x + (size_t)row * 128 + l * 2);
    float s = v.x + v.y, s2 = v.x * v.x + v.y * v.y;
#pragma unroll
    for (int off = 1; off < 64; off <<= 1) {
        s  += __shfl_xor(s, off);
        s2 += __shfl_xor(s2, off);
    }
    float mu = s * (1.f / 128.f);
    float var = s2 * (1.f / 128.f) - mu * mu;
    float rs = rsqrtf(var + EPS_);
    float2 gg = *(const float2*)(g + l * 2);
    float2 bb = *(const float2*)(be + l * 2);
    float ox = (v.x - mu) * rs * gg.x + bb.x;
    float oy = (v.y - mu) * rs * gg.y + bb.y;
    *(unsigned*)(xnb + (size_t)row * 128 + l * 2) = pk2(ox, oy);
}

// ---------------------------------------------------------------------------
// K0b: fp32 -> bf16 convert (8 elems/thread)
// ---------------------------------------------------------------------------
__global__ __launch_bounds__(256) void k_cvt(
    const float* __restrict__ src, unsigned short* __restrict__ dst)
{
    size_t i = ((size_t)blockIdx.x * 256 + threadIdx.x) * 8;
    float4 f0 = *(const float4*)(src + i), f1 = *(const float4*)(src + i + 4);
    uint4 u = { pk2(f0.x, f0.y), pk2(f0.z, f0.w), pk2(f1.x, f1.y), pk2(f1.z, f1.w) };
    *(uint4*)(dst + i) = u;
}

// ---------------------------------------------------------------------------
// K1: QKV GEMM, bf16-native. M=128 x N=128, K=128 one-shot. Grid (64, 24).
// ---------------------------------------------------------------------------
__global__ __launch_bounds__(256) void k_qkv_gemm(
    const unsigned short* __restrict__ xnb, const unsigned short* __restrict__ wb,
    unsigned short* __restrict__ qkv)
{
    __shared__ unsigned short lA[128 * 136];
    __shared__ unsigned short lB[128 * 136];
    const int t = threadIdx.x;
    const int wv = t >> 6, l = t & 63;
    const int lm = l & 15, quad = l >> 4;
    const int row0 = blockIdx.x * 128;
    const int e0   = blockIdx.y * 128;

#pragma unroll
    for (int i = 0; i < 8; ++i) {
        int c = t + 256 * i;  int r = c >> 4, c8 = c & 15;
        *(uint4*)&lA[r * 136 + c8 * 8] =
            *(const uint4*)(xnb + (size_t)(row0 + r) * 128 + c8 * 8);
        *(uint4*)&lB[r * 136 + c8 * 8] =
            *(const uint4*)(wb + (size_t)(e0 + r) * 128 + c8 * 8);
    }
    __syncthreads();

    short8 af[2][4];
#pragma unroll
    for (int mt = 0; mt < 2; ++mt)
#pragma unroll
        for (int ks = 0; ks < 4; ++ks)
            af[mt][ks] = *(short8*)&lA[(wv * 32 + mt * 16 + lm) * 136 + ks * 32 + quad * 8];

    f32x4 acc[2][8];
#pragma unroll
    for (int mt = 0; mt < 2; ++mt)
#pragma unroll
        for (int ct = 0; ct < 8; ++ct) acc[mt][ct] = (f32x4){0.f, 0.f, 0.f, 0.f};
#pragma unroll
    for (int ks = 0; ks < 4; ++ks) {
#pragma unroll
        for (int ct = 0; ct < 8; ++ct) {
            short8 b = *(short8*)&lB[(ct * 16 + lm) * 136 + ks * 32 + quad * 8];
            acc[0][ct] = __builtin_amdgcn_mfma_f32_16x16x32_bf16(af[0][ks], b, acc[0][ct], 0, 0, 0);
            acc[1][ct] = __builtin_amdgcn_mfma_f32_16x16x32_bf16(af[1][ks], b, acc[1][ct], 0, 0, 0);
        }
    }
    __syncthreads();

#pragma unroll
    for (int mt = 0; mt < 2; ++mt)
#pragma unroll
        for (int ct = 0; ct < 8; ++ct)
#pragma unroll
            for (int r = 0; r < 4; ++r)
                lA[(wv * 32 + mt * 16 + quad * 4 + r) * 136 + ct * 16 + lm] =
                    f2bf(acc[mt][ct][r]);
    __syncthreads();
#pragma unroll
    for (int i = 0; i < 8; ++i) {
        int c = t + 256 * i;  int r = c >> 4, c8 = c & 15;
        *(uint4*)(qkv + (size_t)(row0 + r) * QKV_ + e0 + c8 * 8) =
            *(uint4*)&lA[r * 136 + c8 * 8];
    }
}

// ---------------------------------------------------------------------------
// K2: rope Q,K (all heads, n < N-1) + scatter; V -> Vt transpose via LDS.
// (R4-validated version, unchanged)
// ---------------------------------------------------------------------------
__global__ __launch_bounds__(256) void k_rope(
    const unsigned short* __restrict__ qkv, unsigned short* __restrict__ Q,
    unsigned short* __restrict__ K, unsigned short* __restrict__ Vt)
{
    __shared__ unsigned lT[128 * 65];
    const int t = threadIdx.x;
    const int bh = blockIdx.x;
    const int n0 = blockIdx.y * 64;
    const int b = bh >> 3, h = bh & 7;
    const int nn = t >> 2, lg = t & 3;
    const int n = n0 + nn;
    const size_t rowb = ((size_t)b * N_ + n) * QKV_;

#pragma unroll
    for (int part = 0; part < 2; ++part) {
        const int coff = part * 1024 + h * 128;
        unsigned short* dst = part == 0 ? Q : K;
#pragma unroll
        for (int jj = 0; jj < 4; ++jj) {
            const int d0 = (lg + jj * 4) * 8;
            short8 vv = *(const short8*)(qkv + rowb + coff + d0);
            unsigned short* pv = (unsigned short*)&vv;
            if (n != N_ - 1) {
#pragma unroll
                for (int p = 0; p < 4; ++p) {
                    int i0 = (d0 >> 1) + p;
                    float invf = exp2f(-(float)i0 * ROPE_C);
                    float th = (float)n * invf;
                    float cs = __cosf(th), sn = __sinf(th);
                    float e = bf2f(pv[2 * p]), o = bf2f(pv[2 * p + 1]);
                    pv[2 * p]     = f2bf(e * cs - o * sn);
                    pv[2 * p + 1] = f2bf(o * cs + e * sn);
                }
            }
            *(short8*)(dst + ((size_t)bh * N_ + n) * HEAD_ + d0) = vv;
        }
    }

#pragma unroll
    for (int jj = 0; jj < 4; ++jj) {
        const int d0 = (lg + jj * 4) * 8;
        short8 vv = *(const short8*)(qkv + rowb + 2048 + h * 128 + d0);
        unsigned short* pv = (unsigned short*)&vv;
#pragma unroll
        for (int j = 0; j < 8; ++j)
            lT[(d0 + j) * 65 + nn] = pv[j];
    }
    __syncthreads();
    {
        const int d = t >> 1, half = t & 1;
        unsigned short ob[32];
#pragma unroll
        for (int i = 0; i < 32; ++i)
            ob[i] = (unsigned short)lT[d * 65 + half * 32 + i];
        unsigned short* dst = Vt + ((size_t)bh * HEAD_ + d) * N_ + n0 + half * 32;
#pragma unroll
        for (int i = 0; i < 4; ++i)
            *(short8*)(dst + i * 8) = *(short8*)&ob[i * 8];
    }
}

// ---------------------------------------------------------------------------
// K3: flash attention, S^T form. QK MFMA operand-swapped so P exits in
// per-lane key-slots (query=lm, keys=quad*4+r of each 16-key block).
// PV uses the SAME 16x16x32 intrinsic with a k-slot permutation: A = concat
// of two 16-key P blocks (shufflevector), B = two b64 V reads at the matching
// key offsets (MFMA only needs A/B k-slot agreement). No P LDS round-trip.
// LDS 34.8KB. Fixed-shift softmax (exact by shift invariance).
// ---------------------------------------------------------------------------
__global__ __launch_bounds__(256) void k_attn(
    const unsigned short* __restrict__ Q, const unsigned short* __restrict__ K,
    const unsigned short* __restrict__ Vt, unsigned short* __restrict__ Ob)
{
    __shared__ unsigned short lK[64 * 136];
    __shared__ unsigned short lV[128 * 68];

    const int t = threadIdx.x;
    const int w = t >> 6, l = t & 63;
    const int lm = l & 15, quad = l >> 4;
    const int bid = blockIdx.x;
    const int bh = bid & 31;
    const int qt = bid >> 5;          // 0..15
    const int n0 = qt * 128;
    const unsigned short* Qb = Q  + (size_t)bh * N_ * HEAD_;
    const unsigned short* Kb = K  + (size_t)bh * N_ * HEAD_;
    const unsigned short* Vb = Vt + (size_t)bh * N_ * HEAD_;

    // Q fragments (B operand of swapped QK MFMA; A/B lane layouts identical)
    short8 aq[2][4];
#pragma unroll
    for (int tt = 0; tt < 2; ++tt) {
        const unsigned short* qp =
            Qb + ((size_t)(n0 + tt * 64 + w * 16 + lm)) * 128 + quad * 8;
#pragma unroll
        for (int ks = 0; ks < 4; ++ks)
            aq[tt][ks] = *(const short8*)(qp + ks * 32);
    }

    f32x4 Oa[2][8];
#pragma unroll
    for (int tt = 0; tt < 2; ++tt)
#pragma unroll
        for (int i = 0; i < 8; ++i) Oa[tt][i] = (f32x4){0.f, 0.f, 0.f, 0.f};
    float ps0 = 0.f, ps1 = 0.f;      // per-lane partials for row q = lm
    const float C1 = SCALE_ * 1.44269504f;
    const float C0 = -23.08312f;     // -16*log2(e); const shift is exact

    // register prefetch (R8-validated)
    short8 kr[4], vr[4];
#pragma unroll
    for (int i = 0; i < 4; ++i) {
        int c = t + 256 * i;
        kr[i] = *(const short8*)(Kb + ((size_t)(c >> 4)) * 128 + (c & 15) * 8);
        vr[i] = *(const short8*)(Vb + (size_t)(c >> 3) * N_ + (c & 7) * 8);
    }

    for (int jt = 0; jt < 32; ++jt) {
        __syncthreads();
#pragma unroll
        for (int i = 0; i < 4; ++i) {
            int c = t + 256 * i;
            *(short8*)&lK[(c >> 4) * 136 + (c & 15) * 8] = kr[i];
            *(short8*)&lV[(c >> 3) * 68  + (c & 7)  * 8] = vr[i];
        }
        __syncthreads();
        if (jt < 31) {
#pragma unroll
            for (int i = 0; i < 4; ++i) {
                int c = t + 256 * i;
                kr[i] = *(const short8*)(Kb + ((size_t)((jt + 1) * 64 + (c >> 4))) * 128 + (c & 15) * 8);
                vr[i] = *(const short8*)(Vb + (size_t)(c >> 3) * N_ + (jt + 1) * 64 + (c & 7) * 8);
            }
        }

        // S^T = K Q^T per 16-key block nb; exp -> P stays in registers
        short4v pf0[4], pf1[4];
#pragma unroll
        for (int nb = 0; nb < 4; ++nb) {
            f32x4 st0 = (f32x4){0.f, 0.f, 0.f, 0.f};
            f32x4 st1 = (f32x4){0.f, 0.f, 0.f, 0.f};
#pragma unroll
            for (int ks = 0; ks < 4; ++ks) {
                short8 kf = *(short8*)&lK[(nb * 16 + lm) * 136 + ks * 32 + quad * 8];
                st0 = __builtin_amdgcn_mfma_f32_16x16x32_bf16(kf, aq[0][ks], st0, 0, 0, 0);
                st1 = __builtin_amdgcn_mfma_f32_16x16x32_bf16(kf, aq[1][ks], st1, 0, 0, 0);
            }
            unsigned short u0[4], u1[4];
#pragma unroll
            for (int r = 0; r < 4; ++r) {
                float p0 = exp2f(st0[r] * C1 + C0);
                float p1 = exp2f(st1[r] * C1 + C0);
                ps0 += p0;  ps1 += p1;
                u0[r] = f2bf(p0);  u1[r] = f2bf(p1);
            }
            pf0[nb] = *(short4v*)u0;
            pf1[nb] = *(short4v*)u1;
        }

        // O += P V via 16x16x32 with permuted k-slots: chunk c2 pairs blocks
        // 2*c2, 2*c2+1. A = concat(P blocks); B = two b64 V reads at the
        // same key offsets (c2*32+quad*4 and +16).
#pragma unroll
        for (int c2 = 0; c2 < 2; ++c2) {
            short8 ap0 = __builtin_shufflevector(pf0[2 * c2], pf0[2 * c2 + 1],
                                                 0, 1, 2, 3, 4, 5, 6, 7);
            short8 ap1 = __builtin_shufflevector(pf1[2 * c2], pf1[2 * c2 + 1],
                                                 0, 1, 2, 3, 4, 5, 6, 7);
#pragma unroll
            for (int nb8 = 0; nb8 < 8; ++nb8) {
                const int rb = (nb8 * 16 + lm) * 68 + c2 * 32 + quad * 4;
                short4v blo = *(short4v*)&lV[rb];
                short4v bhi = *(short4v*)&lV[rb + 16];
                short8 bv = __builtin_shufflevector(blo, bhi, 0, 1, 2, 3, 4, 5, 6, 7);
                Oa[0][nb8] = __builtin_amdgcn_mfma_f32_16x16x32_bf16(ap0, bv, Oa[0][nb8], 0, 0, 0);
                Oa[1][nb8] = __builtin_amdgcn_mfma_f32_16x16x32_bf16(ap1, bv, Oa[1][nb8], 0, 0, 0);
            }
        }
    }

    // reduce row sums across quads (lanes sharing lm), then redistribute
    ps0 += __shfl_xor(ps0, 16);  ps0 += __shfl_xor(ps0, 32);
    ps1 += __shfl_xor(ps1, 16);  ps1 += __shfl_xor(ps1, 32);

    const int b = bh >> 3, h = bh & 7;
#pragma unroll
    for (int tt = 0; tt < 2; ++tt)
#pragma unroll
        for (int r = 0; r < 4; ++r) {
            float lsum = __shfl(tt == 0 ? ps0 : ps1, (l & 48) | (quad * 4 + r));
            float il = 1.f / lsum;
            int n = n0 + tt * 64 + w * 16 + quad * 4 + r;
            unsigned short* op = Ob + ((size_t)b * N_ + n) * INNER_ + h * HEAD_ + lm;
#pragma unroll
            for (int nb8 = 0; nb8 < 8; ++nb8)
                op[nb8 * 16] = f2bf(Oa[tt][nb8][r] * il);
        }
}

// ---------------------------------------------------------------------------
// K4: output projection, bf16 MFMA. out[8192,128] = Ob @ wob^T + b_out.
// ---------------------------------------------------------------------------
__global__ __launch_bounds__(256) void k_proj(
    const unsigned short* __restrict__ Ob, const unsigned short* __restrict__ wob,
    const float* __restrict__ bias, float* __restrict__ out)
{
    __shared__ unsigned short lA[64 * 136];
    __shared__ unsigned short lB[64 * 136];
    float* lCf = (float*)lA;
    const int t = threadIdx.x;
    const int wv = t >> 6, l = t & 63;
    const int lm = l & 15, quad = l >> 4;
    const int row0 = blockIdx.x * 64;
    const int e0   = blockIdx.y * 64;

    f32x4 acc[4];
#pragma unroll
    for (int ct = 0; ct < 4; ++ct) acc[ct] = (f32x4){0.f, 0.f, 0.f, 0.f};

    for (int kt = 0; kt < 8; ++kt) {
        __syncthreads();
#pragma unroll
        for (int i = 0; i < 4; ++i) {
            int c = t + 256 * i;  int r = c >> 4, c8 = c & 15;
            *(uint4*)&lA[r * 136 + c8 * 8] =
                *(const uint4*)(Ob + (size_t)(row0 + r) * 1024 + kt * 128 + c8 * 8);
            *(uint4*)&lB[r * 136 + c8 * 8] =
                *(const uint4*)(wob + (size_t)(e0 + r) * 1024 + kt * 128 + c8 * 8);
        }
        __syncthreads();
        short8 a_[4];
#pragma unroll
        for (int ks = 0; ks < 4; ++ks)
            a_[ks] = *(short8*)&lA[(wv * 16 + lm) * 136 + ks * 32 + quad * 8];
#pragma unroll
        for (int ks = 0; ks < 4; ++ks)
#pragma unroll
            for (int ct = 0; ct < 4; ++ct) {
                short8 b = *(short8*)&lB[(ct * 16 + lm) * 136 + ks * 32 + quad * 8];
                acc[ct] = __builtin_amdgcn_mfma_f32_16x16x32_bf16(a_[ks], b, acc[ct], 0, 0, 0);
            }
    }
    __syncthreads();
#pragma unroll
    for (int ct = 0; ct < 4; ++ct)
#pragma unroll
        for (int r = 0; r < 4; ++r)
            lCf[(wv * 16 + quad * 4 + r) * 68 + ct * 16 + lm] = acc[ct][r];
    __syncthreads();
#pragma unroll
    for (int i = 0; i < 4; ++i) {
        int c = t + 256 * i;  int r = c >> 4, c4 = c & 15;
        float4 v = *(float4*)&lCf[r * 68 + c4 * 4];
        float4 b4 = *(const float4*)(bias + e0 + c4 * 4);
        v.x += b4.x; v.y += b4.y; v.z += b4.z; v.w += b4.w;
        *(float4*)(out + (size_t)(row0 + r) * 128 + e0 + c4 * 4) = v;
    }
}

// ---------------------------------------------------------------------------
extern "C" void kernel_launch(void* const* d_in, const int* in_sizes, int n_in,
                              void* d_out, int out_size, void* d_ws, size_t ws_size,
                              hipStream_t stream) {
    const float* x      = (const float*)d_in[0];
    const float* gamma  = (const float*)d_in[1];
    const float* beta   = (const float*)d_in[2];
    const float* w_qkv  = (const float*)d_in[3];
    const float* w_out  = (const float*)d_in[4];
    const float* b_out  = (const float*)d_in[5];
    float* out = (float*)d_out;
    char* wsb = (char*)d_ws;
    unsigned short* Q    = (unsigned short*)(wsb);
    unsigned short* K    = (unsigned short*)(wsb + (16ull << 20));
    unsigned short* Vt   = (unsigned short*)(wsb + (32ull << 20));
    unsigned short* qkv  = (unsigned short*)(wsb + (48ull << 20));
    unsigned short* Ob   = (unsigned short*)(wsb + (48ull << 20));  // after qkv dies
    unsigned short* xnb  = (unsigned short*)(wsb + (96ull << 20));
    unsigned short* wqb  = (unsigned short*)(wsb + (98ull << 20));
    unsigned short* wob  = (unsigned short*)(wsb + (99ull << 20));

    k_ln       <<<dim3(2048),    256, 0, stream>>>(x, gamma, beta, xnb);
    k_cvt      <<<dim3(192),     256, 0, stream>>>(w_qkv, wqb);   // 3072*128
    k_cvt      <<<dim3(64),      256, 0, stream>>>(w_out, wob);   // 128*1024
    k_qkv_gemm <<<dim3(64, 24),  256, 0, stream>>>(xnb, wqb, qkv);
    k_rope     <<<dim3(32, 32),  256, 0, stream>>>(qkv, Q, K, Vt);
    k_attn     <<<dim3(512),     256, 0, stream>>>(Q, K, Vt, Ob);
    k_proj     <<<dim3(128, 2),  256, 0, stream>>>(Ob, wob, b_out, out);
}